// Round 1
// baseline (9461.906 us; speedup 1.0000x reference)
//
#include <hip/hip_runtime.h>
#include <cmath>

#define BB 32
#define SS 64
#define TT 16
#define UU 1024
#define EE 256
#define VV 20200
#define G3 3072
#define NBLK 256

// workspace layout (float offsets)
#define WS_XEMBT   0                           // XembT [S][E][B]
#define WS_HT      (WS_XEMBT + SS*EE*BB)       // hT [S+1][U][B]; slot0 = zeros
#define WS_ENC     (WS_HT + (SS+1)*UU*BB)      // encoded [(b*S+s)][U]
#define WS_PREENC  (WS_ENC + BB*SS*UU)         // pre_enc [(b*S+s)][U]
#define WS_Q       (WS_PREENC + BB*SS*UU)      // q [b][U]
#define WS_ESC     (WS_Q + BB*UU)              // scores [b][S]
#define WS_XT      (WS_ESC + BB*SS)            // xT [(U+E)][B]
#define WS_HDECT   (WS_XT + (UU+EE)*BB)        // dec hidden transposed [U][B]
#define WS_HDEC    (WS_HDECT + UU*BB)          // Hdec [(b*T+t)][U]
#define WS_BAR     (WS_HDEC + BB*TT*UU)        // 16 uints of barrier state

__device__ __forceinline__ float sigmoidf_(float x) {
    return 1.0f / (1.0f + expf(-x));
}

// sense-reversing grid barrier, device scope. All blocks guaranteed resident
// (256 blocks, 256 thr, <=24KB LDS -> >=6 blocks/CU capacity).
__device__ __forceinline__ void grid_barrier(unsigned* bar) {
    __syncthreads();
    if (threadIdx.x == 0) {
        unsigned* cnt = bar;
        unsigned* gen = bar + 1;
        unsigned g = __hip_atomic_load(gen, __ATOMIC_RELAXED, __HIP_MEMORY_SCOPE_AGENT);
        __threadfence();  // release prior writes to agent scope
        unsigned a = __hip_atomic_fetch_add(cnt, 1u, __ATOMIC_ACQ_REL, __HIP_MEMORY_SCOPE_AGENT);
        if (a == NBLK - 1u) {
            __hip_atomic_store(cnt, 0u, __ATOMIC_RELAXED, __HIP_MEMORY_SCOPE_AGENT);
            __hip_atomic_store(gen, g + 1u, __ATOMIC_RELEASE, __HIP_MEMORY_SCOPE_AGENT);
        } else {
            while (__hip_atomic_load(gen, __ATOMIC_ACQUIRE, __HIP_MEMORY_SCOPE_AGENT) == g) {
                __builtin_amdgcn_s_sleep(1);
            }
        }
    }
    __syncthreads();
}

// ---------------- prep: embedding gather (transposed) + zero init ----------------
__global__ __launch_bounds__(256) void k_prep(const int* __restrict__ enc_in,
                                              const float* __restrict__ Ee,
                                              float* __restrict__ ws) {
    int gid = blockIdx.x * 256 + threadIdx.x;
    const int NE = SS * EE * BB;            // 524288
    if (gid < NE) {
        int b = gid & 31;
        int e = (gid >> 5) & 255;
        int s = gid >> 13;
        ws[WS_XEMBT + gid] = Ee[(size_t)enc_in[b * SS + s] * EE + e];
    } else if (gid < NE + UU * BB) {
        ws[WS_HT + (gid - NE)] = 0.0f;      // h(-1) = 0
    } else if (gid < NE + UU * BB + 16) {
        ((unsigned*)(ws + WS_BAR))[gid - NE - UU * BB] = 0u;
    }
}

// ---------------- encoder: 64 GRU steps, persistent grid ----------------
// block bid owns h-cols [bid*4, bid*4+4). thread: kp=tid>>5 (split-K 8),
// rg=(tid>>2)&7 (4 rows each), cg=tid&3 (gate-col jj). micro 4 rows x 3 gate-cols.
__global__ __launch_bounds__(256) void k_encoder(const float* __restrict__ Wh,
                                                 const float* __restrict__ Wx,
                                                 const float* __restrict__ b_in,
                                                 const float* __restrict__ b_rec,
                                                 float* __restrict__ ws) {
    float* XembT = ws + WS_XEMBT;
    float* hT = ws + WS_HT;
    float* enc = ws + WS_ENC;
    unsigned* bar = (unsigned*)(ws + WS_BAR);

    const int tid = threadIdx.x;
    const int bid = blockIdx.x;
    const int kp = tid >> 5;
    const int rg = (tid >> 2) & 7;
    const int cg = tid & 3;
    const int hb = bid * 4;
    const int wc0 = hb + cg;            // z gate col
    const int wc1 = 1024 + hb + cg;     // r gate col
    const int wc2 = 2048 + hb + cg;     // c gate col

    __shared__ float redH[384 * 8];
    __shared__ float redX[384 * 8];

    for (int t = 0; t < SS; ++t) {
        const float* hprev = hT + (size_t)t * (UU * BB);
        float ah[4][3] = {{0.f}};
        float ax[4][3] = {{0.f}};

        // h-part: K=1024, this thread's chunk of 128
        #pragma unroll 4
        for (int k = kp * 128; k < kp * 128 + 128; ++k) {
            float4 hv = *(const float4*)(hprev + (size_t)k * BB + rg * 4);
            const float* wrow = Wh + (size_t)k * G3;
            float w0 = wrow[wc0], w1 = wrow[wc1], w2 = wrow[wc2];
            ah[0][0] += hv.x * w0; ah[1][0] += hv.y * w0; ah[2][0] += hv.z * w0; ah[3][0] += hv.w * w0;
            ah[0][1] += hv.x * w1; ah[1][1] += hv.y * w1; ah[2][1] += hv.z * w1; ah[3][1] += hv.w * w1;
            ah[0][2] += hv.x * w2; ah[1][2] += hv.y * w2; ah[2][2] += hv.z * w2; ah[3][2] += hv.w * w2;
        }
        // x-part: K=256, chunk of 32 (kept separate: c-gate needs xh and hh split)
        const float* xt = XembT + (size_t)t * (EE * BB);
        #pragma unroll 4
        for (int k = kp * 32; k < kp * 32 + 32; ++k) {
            float4 xv = *(const float4*)(xt + (size_t)k * BB + rg * 4);
            const float* wrow = Wx + (size_t)k * G3;
            float w0 = wrow[wc0], w1 = wrow[wc1], w2 = wrow[wc2];
            ax[0][0] += xv.x * w0; ax[1][0] += xv.y * w0; ax[2][0] += xv.z * w0; ax[3][0] += xv.w * w0;
            ax[0][1] += xv.x * w1; ax[1][1] += xv.y * w1; ax[2][1] += xv.z * w1; ax[3][1] += xv.w * w1;
            ax[0][2] += xv.x * w2; ax[1][2] += xv.y * w2; ax[2][2] += xv.z * w2; ax[3][2] += xv.w * w2;
        }
        #pragma unroll
        for (int c = 0; c < 3; ++c)
            #pragma unroll
            for (int i = 0; i < 4; ++i) {
                int o = (c * 4 + cg) * 32 + rg * 4 + i;
                redH[o * 8 + kp] = ah[i][c];
                redX[o * 8 + kp] = ax[i][c];
            }
        __syncthreads();
        if (tid < 128) {
            int r = tid & 31, jj = tid >> 5;
            int j = hb + jj;
            float hz = 0, hr = 0, hc = 0, xz = 0, xr = 0, xc = 0;
            #pragma unroll
            for (int p = 0; p < 8; ++p) {
                hz += redH[((0 + jj) * 32 + r) * 8 + p];
                hr += redH[((4 + jj) * 32 + r) * 8 + p];
                hc += redH[((8 + jj) * 32 + r) * 8 + p];
                xz += redX[((0 + jj) * 32 + r) * 8 + p];
                xr += redX[((4 + jj) * 32 + r) * 8 + p];
                xc += redX[((8 + jj) * 32 + r) * 8 + p];
            }
            xz += b_in[j]; xr += b_in[1024 + j]; xc += b_in[2048 + j];
            hz += b_rec[j]; hr += b_rec[1024 + j]; hc += b_rec[2048 + j];
            float z = sigmoidf_(xz + hz);
            float rr = sigmoidf_(xr + hr);
            float cc = tanhf(xc + rr * hc);
            float hold = hprev[(size_t)j * BB + r];
            float hnew = z * hold + (1.0f - z) * cc;
            hT[(size_t)(t + 1) * (UU * BB) + (size_t)j * BB + r] = hnew;
            enc[((size_t)r * SS + t) * UU + j] = hnew;
        }
        grid_barrier(bar);
    }
}

// ---------------- generic fp32 GEMM: C[M,N] = A[M,K]@B[K,N] + bias ----------------
// tile 64(M) x 128(N), BK=16, 256 threads, micro 8x4. M%64==0, K%16==0; N guarded.
__global__ __launch_bounds__(256) void k_gemm(const float* __restrict__ A,
                                              const float* __restrict__ Bm,
                                              const float* __restrict__ bias,
                                              float* __restrict__ C,
                                              int M, int N, int K) {
    __shared__ float As[16][68];
    __shared__ float Bs[16][132];
    const int rb = blockIdx.x * 64;
    const int cb = blockIdx.y * 128;
    const int tid = threadIdx.x;
    const int cg = tid & 31;   // col group: 4 cols
    const int rg = tid >> 5;   // row group: 8 rows
    float acc[8][4] = {{0.f}};

    const int arow = tid >> 2, akq = (tid & 3) * 4;
    const int bkk = tid >> 4, bc8 = (tid & 15) * 8;
    const bool nfull = (cb + 128 <= N);

    for (int k0 = 0; k0 < K; k0 += 16) {
        {
            float4 a4 = *(const float4*)(A + (size_t)(rb + arow) * K + k0 + akq);
            As[akq + 0][arow] = a4.x; As[akq + 1][arow] = a4.y;
            As[akq + 2][arow] = a4.z; As[akq + 3][arow] = a4.w;
        }
        {
            int col = cb + bc8;
            const float* bp = Bm + (size_t)(k0 + bkk) * N + col;
            if (nfull) {
                float4 x0 = *(const float4*)bp;
                float4 x1 = *(const float4*)(bp + 4);
                Bs[bkk][bc8 + 0] = x0.x; Bs[bkk][bc8 + 1] = x0.y; Bs[bkk][bc8 + 2] = x0.z; Bs[bkk][bc8 + 3] = x0.w;
                Bs[bkk][bc8 + 4] = x1.x; Bs[bkk][bc8 + 5] = x1.y; Bs[bkk][bc8 + 6] = x1.z; Bs[bkk][bc8 + 7] = x1.w;
            } else {
                #pragma unroll
                for (int j = 0; j < 8; ++j)
                    Bs[bkk][bc8 + j] = (col + j < N) ? bp[j] : 0.0f;
            }
        }
        __syncthreads();
        #pragma unroll
        for (int kk = 0; kk < 16; ++kk) {
            float4 a0 = *(const float4*)&As[kk][rg * 8];
            float4 a1 = *(const float4*)&As[kk][rg * 8 + 4];
            float4 b0 = *(const float4*)&Bs[kk][cg * 4];
            float av[8] = {a0.x, a0.y, a0.z, a0.w, a1.x, a1.y, a1.z, a1.w};
            float bv[4] = {b0.x, b0.y, b0.z, b0.w};
            #pragma unroll
            for (int i = 0; i < 8; ++i)
                #pragma unroll
                for (int j = 0; j < 4; ++j)
                    acc[i][j] += av[i] * bv[j];
        }
        __syncthreads();
    }
    const int col0 = cb + cg * 4;
    const bool cfull = (col0 + 4 <= N);
    #pragma unroll
    for (int i = 0; i < 8; ++i) {
        int row = rb + rg * 8 + i;
        float* cp = C + (size_t)row * N + col0;
        if (cfull) {
            float4 o;
            o.x = acc[i][0] + bias[col0 + 0];
            o.y = acc[i][1] + bias[col0 + 1];
            o.z = acc[i][2] + bias[col0 + 2];
            o.w = acc[i][3] + bias[col0 + 3];
            *(float4*)cp = o;
        } else {
            #pragma unroll
            for (int j = 0; j < 4; ++j)
                if (col0 + j < N) cp[j] = acc[i][j] + bias[col0 + j];
        }
    }
}

// ---------------- decoder: 16 steps x 4 phases, persistent grid ----------------
__global__ __launch_bounds__(256) void k_decoder(const float* __restrict__ W2,
                                                 const float* __restrict__ b2,
                                                 const float* __restrict__ Va,
                                                 const float* __restrict__ bv,
                                                 const float* __restrict__ Wxd,
                                                 const float* __restrict__ b_in,
                                                 const float* __restrict__ b_rec,
                                                 const float* __restrict__ Ed,
                                                 const int* __restrict__ teacher,
                                                 float* __restrict__ ws) {
    float* hT = ws + WS_HT;
    float* enc = ws + WS_ENC;
    float* pre = ws + WS_PREENC;
    float* q = ws + WS_Q;
    float* esc = ws + WS_ESC;
    float* xT = ws + WS_XT;
    float* hdT = ws + WS_HDECT;
    float* Hd = ws + WS_HDEC;
    unsigned* bar = (unsigned*)(ws + WS_BAR) + 2;

    const int tid = threadIdx.x;
    const int bid = blockIdx.x;
    __shared__ float sh[384 * 8];
    __shared__ float eL[64];
    __shared__ float attnL[64];

    for (int t = 0; t < TT; ++t) {
        const float* hsrc = (t == 0) ? (hT + (size_t)SS * (UU * BB)) : hdT;

        // ---- S1: q = dec_h @ W2 + b2 ----
        {
            const int kp = tid >> 5, rg = (tid >> 2) & 7, cq = tid & 3;
            const int qc = bid * 4 + cq;
            float a0 = 0, a1 = 0, a2 = 0, a3 = 0;
            #pragma unroll 4
            for (int k = kp * 128; k < kp * 128 + 128; ++k) {
                float4 hv = *(const float4*)(hsrc + (size_t)k * BB + rg * 4);
                float w = W2[(size_t)k * UU + qc];
                a0 += hv.x * w; a1 += hv.y * w; a2 += hv.z * w; a3 += hv.w * w;
            }
            sh[(cq * 32 + rg * 4 + 0) * 8 + kp] = a0;
            sh[(cq * 32 + rg * 4 + 1) * 8 + kp] = a1;
            sh[(cq * 32 + rg * 4 + 2) * 8 + kp] = a2;
            sh[(cq * 32 + rg * 4 + 3) * 8 + kp] = a3;
        }
        __syncthreads();
        if (tid < 128) {
            int cq = tid >> 5, r = tid & 31;
            float s = 0;
            #pragma unroll
            for (int p = 0; p < 8; ++p) s += sh[(cq * 32 + r) * 8 + p];
            q[(size_t)r * UU + bid * 4 + cq] = s + b2[bid * 4 + cq];
        }
        grid_barrier(bar);

        // ---- S2: scores e[b][s] = tanh(pre_enc + q) . Va + bv ----
        {
            const int b = bid >> 3, s0 = (bid & 7) * 8;
            const int pi = tid >> 5, kq = tid & 31;
            const int srow = s0 + pi;
            const float* pe = pre + ((size_t)b * SS + srow) * UU;
            const float* qb = q + (size_t)b * UU;
            float acc = 0;
            #pragma unroll
            for (int kk = 0; kk < 8; ++kk) {
                int k = kq * 32 + kk * 4;
                float4 p4 = *(const float4*)(pe + k);
                float4 q4 = *(const float4*)(qb + k);
                float4 v4 = *(const float4*)(Va + k);
                acc += tanhf(p4.x + q4.x) * v4.x + tanhf(p4.y + q4.y) * v4.y +
                       tanhf(p4.z + q4.z) * v4.z + tanhf(p4.w + q4.w) * v4.w;
            }
            #pragma unroll
            for (int m = 16; m >= 1; m >>= 1) acc += __shfl_xor(acc, m, 32);
            if (kq == 0) esc[b * SS + srow] = acc + bv[0];
        }
        grid_barrier(bar);

        // ---- S3: softmax + ctx (coalesced over U) + embed gather into xT ----
        {
            const int b = bid >> 3, ug = bid & 7;
            if (tid < 64) eL[tid] = esc[b * SS + tid];
            __syncthreads();
            if (tid < 64) {
                float v = eL[tid];
                float m = v;
                #pragma unroll
                for (int mm = 32; mm >= 1; mm >>= 1) m = fmaxf(m, __shfl_xor(m, mm, 64));
                float p = expf(v - m);
                float sum = p;
                #pragma unroll
                for (int mm = 32; mm >= 1; mm >>= 1) sum += __shfl_xor(sum, mm, 64);
                attnL[tid] = p / sum;
            }
            __syncthreads();
            const int u = ug * 128 + (tid & 127), sp = tid >> 7;
            float acc = 0;
            #pragma unroll 8
            for (int i = 0; i < 32; ++i) {
                int srow = sp * 32 + i;
                acc += attnL[srow] * enc[((size_t)b * SS + srow) * UU + u];
            }
            sh[(tid & 127) * 2 + sp] = acc;
            __syncthreads();
            if (tid < 128) xT[(size_t)(ug * 128 + tid) * BB + b] = sh[tid * 2] + sh[tid * 2 + 1];
            if (tid < 32) {
                int e = ug * 32 + tid;
                xT[(size_t)(UU + e) * BB + b] = Ed[(size_t)teacher[b * TT + t] * EE + e];
            }
        }
        grid_barrier(bar);

        // ---- S4: gx = x @ dec_Wx, gates with gh = b_rec (h0_dec == 0), h_new ----
        {
            const int kp = tid >> 5, rg = (tid >> 2) & 7, cgl = tid & 3;
            const int wc0 = bid * 4 + cgl, wc1 = 1024 + bid * 4 + cgl, wc2 = 2048 + bid * 4 + cgl;
            float a[4][3] = {{0.f}};
            #pragma unroll 4
            for (int k = kp * 160; k < kp * 160 + 160; ++k) {
                float4 xv = *(const float4*)(xT + (size_t)k * BB + rg * 4);
                const float* wrow = Wxd + (size_t)k * G3;
                float w0 = wrow[wc0], w1 = wrow[wc1], w2 = wrow[wc2];
                a[0][0] += xv.x * w0; a[1][0] += xv.y * w0; a[2][0] += xv.z * w0; a[3][0] += xv.w * w0;
                a[0][1] += xv.x * w1; a[1][1] += xv.y * w1; a[2][1] += xv.z * w1; a[3][1] += xv.w * w1;
                a[0][2] += xv.x * w2; a[1][2] += xv.y * w2; a[2][2] += xv.z * w2; a[3][2] += xv.w * w2;
            }
            #pragma unroll
            for (int c = 0; c < 3; ++c)
                #pragma unroll
                for (int i = 0; i < 4; ++i)
                    sh[((c * 4 + cgl) * 32 + rg * 4 + i) * 8 + kp] = a[i][c];
        }
        __syncthreads();
        if (tid < 128) {
            int bb = tid & 31, jj = tid >> 5;
            int j = bid * 4 + jj;
            float sz = 0, sr = 0, sc = 0;
            #pragma unroll
            for (int p = 0; p < 8; ++p) {
                sz += sh[((0 + jj) * 32 + bb) * 8 + p];
                sr += sh[((4 + jj) * 32 + bb) * 8 + p];
                sc += sh[((8 + jj) * 32 + bb) * 8 + p];
            }
            float z = sigmoidf_(sz + b_in[j] + b_rec[j]);
            float rr = sigmoidf_(sr + b_in[1024 + j] + b_rec[1024 + j]);
            float cc = tanhf(sc + b_in[2048 + j] + rr * b_rec[2048 + j]);
            float h = (1.0f - z) * cc;   // z*h0 + (1-z)*c with h0=0
            Hd[((size_t)bb * TT + t) * UU + j] = h;
            hdT[(size_t)j * BB + bb] = h;
        }
        grid_barrier(bar);
    }
}

// ---------------- argmax with numpy first-index tie-break ----------------
__global__ __launch_bounds__(256) void k_argmax(const float* __restrict__ logits,
                                                float* __restrict__ outp) {
    const int row = blockIdx.x;  // b*T + t
    const float* lr = logits + (size_t)row * VV;
    const int tid = threadIdx.x;
    float best = -INFINITY;
    int bidx = 0x7fffffff;
    for (int c = tid; c < VV; c += 256) {
        float v = lr[c];
        if (v > best) { best = v; bidx = c; }   // ascending scan -> first max kept
    }
    __shared__ float bv_[256];
    __shared__ int bi_[256];
    bv_[tid] = best; bi_[tid] = bidx;
    __syncthreads();
    for (int s2 = 128; s2 > 0; s2 >>= 1) {
        if (tid < s2) {
            float ov = bv_[tid + s2]; int oi = bi_[tid + s2];
            if (ov > bv_[tid] || (ov == bv_[tid] && oi < bi_[tid])) {
                bv_[tid] = ov; bi_[tid] = oi;
            }
        }
        __syncthreads();
    }
    if (tid == 0) outp[row] = (float)bi_[0];
}

extern "C" void kernel_launch(void* const* d_in, const int* in_sizes, int n_in,
                              void* d_out, int out_size, void* d_ws, size_t ws_size,
                              hipStream_t stream) {
    const int* enc_in = (const int*)d_in[0];
    const int* teacher = (const int*)d_in[1];
    const float* Ee = (const float*)d_in[4];
    const float* eWx = (const float*)d_in[5];
    const float* eWh = (const float*)d_in[6];
    const float* eb_in = (const float*)d_in[7];
    const float* eb_rec = (const float*)d_in[8];
    const float* Ed = (const float*)d_in[9];
    const float* dWx = (const float*)d_in[10];
    // d_in[11] dec_Wh is structurally unused: h0_dec == 0 -> gh == b_rec
    const float* db_in = (const float*)d_in[12];
    const float* db_rec = (const float*)d_in[13];
    const float* W1 = (const float*)d_in[14];
    const float* b1 = (const float*)d_in[15];
    const float* W2 = (const float*)d_in[16];
    const float* b2 = (const float*)d_in[17];
    const float* Va = (const float*)d_in[18];
    const float* bvv = (const float*)d_in[19];
    const float* Wf = (const float*)d_in[20];
    const float* bf = (const float*)d_in[21];
    float* ws = (float*)d_ws;
    float* out = (float*)d_out;

    // prep: embed (524288) + zero hT slot0 (32768) + zero barriers (16)
    k_prep<<<dim3((SS * EE * BB + UU * BB + 16 + 255) / 256), dim3(256), 0, stream>>>(enc_in, Ee, ws);

    // encoder recurrence (persistent, 64 steps, 1 grid barrier/step)
    k_encoder<<<dim3(NBLK), dim3(256), 0, stream>>>(eWh, eWx, eb_in, eb_rec, ws);

    // pre_enc = encoded @ W1 + b1  : [2048,1024]x[1024,1024]
    k_gemm<<<dim3(32, 8), dim3(256), 0, stream>>>(ws + WS_ENC, W1, b1, ws + WS_PREENC, 2048, 1024, 1024);

    // decoder (persistent, 16 steps x 4 phases)
    k_decoder<<<dim3(NBLK), dim3(256), 0, stream>>>(W2, b2, Va, bvv, dWx, db_in, db_rec, Ed, teacher, ws);

    // logits = Hdec @ Wf + bf : [512,1024]x[1024,20200] -> d_out
    k_gemm<<<dim3(8, 158), dim3(256), 0, stream>>>(ws + WS_HDEC, Wf, bf, out, BB * TT, VV, 1024);

    // predictions = argmax(logits) as float
    k_argmax<<<dim3(BB * TT), dim3(256), 0, stream>>>(out, out + (size_t)BB * TT * VV);
}

// Round 2
// 7430.487 us; speedup vs baseline: 1.2734x; 1.2734x over previous
//
#include <hip/hip_runtime.h>
#include <cmath>

#define BB 32
#define SS 64
#define TT 16
#define UU 1024
#define EE 256
#define VV 20200
#define G3 3072
#define NBLK 256

// workspace layout (float offsets) — total 7,112,720 floats (28.5 MB, < round-1's 29.9 MB proven)
#define WS_XEMBT 0                          // XembT [S][E][B]
#define WS_HT    (WS_XEMBT + SS*EE*BB)      // hT: 2 ping-pong slots of [U][B]
#define WS_ENC   (WS_HT + 2*UU*BB)          // encoded [(b*S+s)][U]
#define WS_PRE   (WS_ENC + BB*SS*UU)        // pre_enc [(b*S+s)][U]
#define WS_Q     (WS_PRE + BB*SS*UU)        // q [b][U]
#define WS_ESC   (WS_Q + BB*UU)             // scores [b][S]
#define WS_XT    (WS_ESC + BB*SS)           // ctx transposed [U][B]
#define WS_HDT   (WS_XT + UU*BB)            // dec hidden transposed [U][B]
#define WS_HD    (WS_HDT + UU*BB)           // Hdec [(b*T+t)][U]
#define WS_DEMB  (WS_HD + BB*TT*UU)         // Demb [(t*B+b)][E]
#define WS_GXD   (WS_DEMB + BB*TT*EE)       // GXd  [(t*B+b)][3U]  (emb@Wxd_bot + b_in)
#define WS_BAR   (WS_GXD + BB*TT*G3)        // barrier state (uints)

__device__ __forceinline__ float sigmoidf_(float x) {
    return 1.0f / (1.0f + expf(-x));
}

// sense-reversing grid barrier, device scope (256 blocks, all resident)
__device__ __forceinline__ void grid_barrier(unsigned* bar) {
    __syncthreads();
    if (threadIdx.x == 0) {
        unsigned* cnt = bar;
        unsigned* gen = bar + 1;
        unsigned g = __hip_atomic_load(gen, __ATOMIC_RELAXED, __HIP_MEMORY_SCOPE_AGENT);
        __threadfence();
        unsigned a = __hip_atomic_fetch_add(cnt, 1u, __ATOMIC_ACQ_REL, __HIP_MEMORY_SCOPE_AGENT);
        if (a == NBLK - 1u) {
            __hip_atomic_store(cnt, 0u, __ATOMIC_RELAXED, __HIP_MEMORY_SCOPE_AGENT);
            __hip_atomic_store(gen, g + 1u, __ATOMIC_RELEASE, __HIP_MEMORY_SCOPE_AGENT);
        } else {
            while (__hip_atomic_load(gen, __ATOMIC_ACQUIRE, __HIP_MEMORY_SCOPE_AGENT) == g) {
                __builtin_amdgcn_s_sleep(1);
            }
        }
    }
    __syncthreads();
}

// ---------------- prep: gathers + zero init ----------------
__global__ __launch_bounds__(256) void k_prep(const int* __restrict__ enc_in,
                                              const float* __restrict__ Ee,
                                              const int* __restrict__ teacher,
                                              const float* __restrict__ Ed,
                                              float* __restrict__ ws) {
    int gid = blockIdx.x * 256 + threadIdx.x;
    const int NE = SS * EE * BB;               // 524288
    const int NH = UU * BB;                    // 32768
    const int ND = BB * TT * EE;               // 131072
    if (gid < NE) {
        int b = gid & 31;
        int e = (gid >> 5) & 255;
        int s = gid >> 13;
        ws[WS_XEMBT + gid] = Ee[(size_t)enc_in[b * SS + s] * EE + e];
    } else if (gid < NE + NH) {
        ws[WS_HT + (gid - NE)] = 0.0f;         // h(-1) = 0 (slot 0)
    } else if (gid < NE + NH + ND) {
        int idx = gid - NE - NH;
        int e = idx & 255;
        int row = idx >> 8;                     // t*32 + b
        int t = row >> 5, b = row & 31;
        ws[WS_DEMB + idx] = Ed[(size_t)teacher[b * TT + t] * EE + e];
    } else if (gid < NE + NH + ND + 16) {
        ((unsigned*)(ws + WS_BAR))[gid - NE - NH - ND] = 0u;
    }
}

// ---------------- encoder: 64 GRU steps, persistent grid, weights in LDS ----------------
// 256 thr = 4 waves; wave wv owns gate-col j = bid*4+wv. lane: kp=lane&7 (split-K in-wave),
// rg=lane>>3 (4 batch rows each). k interleaved: k = kp + 8*kk -> 1KB-coalesced h loads.
__global__ __launch_bounds__(256) void k_encoder(const float* __restrict__ Wh,
                                                 const float* __restrict__ Wx,
                                                 const float* __restrict__ b_in,
                                                 const float* __restrict__ b_rec,
                                                 float* __restrict__ ws) {
    float* XembT = ws + WS_XEMBT;
    float* hT = ws + WS_HT;
    float* enc = ws + WS_ENC;
    unsigned* bar = (unsigned*)(ws + WS_BAR);

    __shared__ float Whs[12288];   // [k][12] : 3 gates x 4 cols
    __shared__ float Wxs[3072];

    const int tid = threadIdx.x;
    const int bid = blockIdx.x;
    const int wv = tid >> 6;
    const int lane = tid & 63;
    const int kp = lane & 7;
    const int rg = lane >> 3;
    const int j = bid * 4 + wv;

    // preload weight tiles (once)
    for (int k = tid; k < 1024; k += 256) {
        #pragma unroll
        for (int g = 0; g < 3; ++g) {
            float4 v = *(const float4*)(Wh + (size_t)k * G3 + g * 1024 + bid * 4);
            *(float4*)&Whs[k * 12 + g * 4] = v;
        }
    }
    if (tid < 256) {
        int k = tid;
        #pragma unroll
        for (int g = 0; g < 3; ++g) {
            float4 v = *(const float4*)(Wx + (size_t)k * G3 + g * 1024 + bid * 4);
            *(float4*)&Wxs[k * 12 + g * 4] = v;
        }
    }
    __syncthreads();

    const float bz_in = b_in[j], br_in = b_in[1024 + j], bc_in = b_in[2048 + j];
    const float bz_rc = b_rec[j], br_rc = b_rec[1024 + j], bc_rc = b_rec[2048 + j];

    for (int t = 0; t < SS; ++t) {
        const float* hprev = hT + (t & 1) * (UU * BB);
        float* hnext = hT + ((t & 1) ^ 1) * (UU * BB);

        float az[4] = {0.f, 0.f, 0.f, 0.f};
        float arr[4] = {0.f, 0.f, 0.f, 0.f};
        float ahh[4] = {0.f, 0.f, 0.f, 0.f};
        float axh[4] = {0.f, 0.f, 0.f, 0.f};

        // ---- h @ Wh : K=1024, 128 k per thread, 8-deep rotated prefetch ----
        {
            const float* hp = hprev + kp * 32 + rg * 4;
            float4 cbuf[8], nbuf[8];
            #pragma unroll
            for (int u = 0; u < 8; ++u) cbuf[u] = *(const float4*)(hp + u * 256);
            #pragma unroll
            for (int g = 0; g < 16; ++g) {
                if (g < 15) {
                    #pragma unroll
                    for (int u = 0; u < 8; ++u)
                        nbuf[u] = *(const float4*)(hp + ((g + 1) * 8 + u) * 256);
                }
                #pragma unroll
                for (int u = 0; u < 8; ++u) {
                    int k = kp + 8 * (g * 8 + u);
                    float w0 = Whs[k * 12 + wv];
                    float w1 = Whs[k * 12 + 4 + wv];
                    float w2 = Whs[k * 12 + 8 + wv];
                    float4 hv = cbuf[u];
                    az[0] += hv.x * w0; az[1] += hv.y * w0; az[2] += hv.z * w0; az[3] += hv.w * w0;
                    arr[0] += hv.x * w1; arr[1] += hv.y * w1; arr[2] += hv.z * w1; arr[3] += hv.w * w1;
                    ahh[0] += hv.x * w2; ahh[1] += hv.y * w2; ahh[2] += hv.z * w2; ahh[3] += hv.w * w2;
                }
                if (g < 15) {
                    #pragma unroll
                    for (int u = 0; u < 8; ++u) cbuf[u] = nbuf[u];
                }
            }
        }
        // ---- x @ Wx : K=256, 32 k per thread ----
        {
            const float* xp = XembT + t * (EE * BB) + kp * 32 + rg * 4;
            #pragma unroll
            for (int g = 0; g < 4; ++g) {
                float4 xv[8];
                #pragma unroll
                for (int u = 0; u < 8; ++u) xv[u] = *(const float4*)(xp + (g * 8 + u) * 256);
                #pragma unroll
                for (int u = 0; u < 8; ++u) {
                    int k = kp + 8 * (g * 8 + u);
                    float w0 = Wxs[k * 12 + wv];
                    float w1 = Wxs[k * 12 + 4 + wv];
                    float w2 = Wxs[k * 12 + 8 + wv];
                    float4 v = xv[u];
                    az[0] += v.x * w0; az[1] += v.y * w0; az[2] += v.z * w0; az[3] += v.w * w0;
                    arr[0] += v.x * w1; arr[1] += v.y * w1; arr[2] += v.z * w1; arr[3] += v.w * w1;
                    axh[0] += v.x * w2; axh[1] += v.y * w2; axh[2] += v.z * w2; axh[3] += v.w * w2;
                }
            }
        }
        // ---- in-wave split-K reduce (kp lives in lane bits 0..2) ----
        #pragma unroll
        for (int m = 1; m <= 4; m <<= 1) {
            #pragma unroll
            for (int i = 0; i < 4; ++i) {
                az[i] += __shfl_xor(az[i], m, 64);
                arr[i] += __shfl_xor(arr[i], m, 64);
                ahh[i] += __shfl_xor(ahh[i], m, 64);
                axh[i] += __shfl_xor(axh[i], m, 64);
            }
        }
        if (kp == 0) {
            #pragma unroll
            for (int i = 0; i < 4; ++i) {
                int r = rg * 4 + i;
                float z = sigmoidf_(az[i] + bz_in + bz_rc);
                float rr = sigmoidf_(arr[i] + br_in + br_rc);
                float cc = tanhf(axh[i] + bc_in + rr * (ahh[i] + bc_rc));
                float hold = hprev[j * 32 + r];
                float hnew = z * hold + (1.0f - z) * cc;
                hnext[j * 32 + r] = hnew;
                enc[((size_t)r * SS + t) * UU + j] = hnew;
            }
        }
        grid_barrier(bar);
    }
}

// ---------------- generic fp32 GEMM: C[M,N] = A[M,K]@B[K,N] + bias (r1, proven) ----------------
__global__ __launch_bounds__(256) void k_gemm(const float* __restrict__ A,
                                              const float* __restrict__ Bm,
                                              const float* __restrict__ bias,
                                              float* __restrict__ C,
                                              int M, int N, int K) {
    __shared__ float As[16][68];
    __shared__ float Bs[16][132];
    const int rb = blockIdx.x * 64;
    const int cb = blockIdx.y * 128;
    const int tid = threadIdx.x;
    const int cg = tid & 31;
    const int rg = tid >> 5;
    float acc[8][4] = {{0.f}};

    const int arow = tid >> 2, akq = (tid & 3) * 4;
    const int bkk = tid >> 4, bc8 = (tid & 15) * 8;
    const bool nfull = (cb + 128 <= N);

    for (int k0 = 0; k0 < K; k0 += 16) {
        {
            float4 a4 = *(const float4*)(A + (size_t)(rb + arow) * K + k0 + akq);
            As[akq + 0][arow] = a4.x; As[akq + 1][arow] = a4.y;
            As[akq + 2][arow] = a4.z; As[akq + 3][arow] = a4.w;
        }
        {
            int col = cb + bc8;
            const float* bp = Bm + (size_t)(k0 + bkk) * N + col;
            if (nfull) {
                float4 x0 = *(const float4*)bp;
                float4 x1 = *(const float4*)(bp + 4);
                Bs[bkk][bc8 + 0] = x0.x; Bs[bkk][bc8 + 1] = x0.y; Bs[bkk][bc8 + 2] = x0.z; Bs[bkk][bc8 + 3] = x0.w;
                Bs[bkk][bc8 + 4] = x1.x; Bs[bkk][bc8 + 5] = x1.y; Bs[bkk][bc8 + 6] = x1.z; Bs[bkk][bc8 + 7] = x1.w;
            } else {
                #pragma unroll
                for (int jj = 0; jj < 8; ++jj)
                    Bs[bkk][bc8 + jj] = (col + jj < N) ? bp[jj] : 0.0f;
            }
        }
        __syncthreads();
        #pragma unroll
        for (int kk = 0; kk < 16; ++kk) {
            float4 a0 = *(const float4*)&As[kk][rg * 8];
            float4 a1 = *(const float4*)&As[kk][rg * 8 + 4];
            float4 b0 = *(const float4*)&Bs[kk][cg * 4];
            float av[8] = {a0.x, a0.y, a0.z, a0.w, a1.x, a1.y, a1.z, a1.w};
            float bv[4] = {b0.x, b0.y, b0.z, b0.w};
            #pragma unroll
            for (int i = 0; i < 8; ++i)
                #pragma unroll
                for (int jj = 0; jj < 4; ++jj)
                    acc[i][jj] += av[i] * bv[jj];
        }
        __syncthreads();
    }
    const int col0 = cb + cg * 4;
    const bool cfull = (col0 + 4 <= N);
    #pragma unroll
    for (int i = 0; i < 8; ++i) {
        int row = rb + rg * 8 + i;
        float* cp = C + (size_t)row * N + col0;
        if (cfull) {
            float4 o;
            o.x = acc[i][0] + bias[col0 + 0];
            o.y = acc[i][1] + bias[col0 + 1];
            o.z = acc[i][2] + bias[col0 + 2];
            o.w = acc[i][3] + bias[col0 + 3];
            *(float4*)cp = o;
        } else {
            #pragma unroll
            for (int jj = 0; jj < 4; ++jj)
                if (col0 + jj < N) cp[jj] = acc[i][jj] + bias[col0 + jj];
        }
    }
}

// ---------------- decoder: 16 steps x 4 phases, persistent grid ----------------
__global__ __launch_bounds__(256) void k_decoder(const float* __restrict__ W2,
                                                 const float* __restrict__ b2,
                                                 const float* __restrict__ Va,
                                                 const float* __restrict__ bv,
                                                 const float* __restrict__ Wxd,
                                                 const float* __restrict__ b_rec,
                                                 float* __restrict__ ws) {
    float* hT = ws + WS_HT;            // slot 0 = encoder final hidden
    float* enc = ws + WS_ENC;
    float* pre = ws + WS_PRE;
    float* q = ws + WS_Q;
    float* esc = ws + WS_ESC;
    float* xT = ws + WS_XT;
    float* hdT = ws + WS_HDT;
    float* Hd = ws + WS_HD;
    float* GXd = ws + WS_GXD;
    unsigned* bar = (unsigned*)(ws + WS_BAR) + 2;

    __shared__ float Wxds[12288];      // ctx-part weight tile [k][12]
    __shared__ float eL[64];
    __shared__ float attnL[64];
    __shared__ float shs[256];

    const int tid = threadIdx.x;
    const int bid = blockIdx.x;
    const int wv = tid >> 6;
    const int lane = tid & 63;

    // preload Wxd rows 0..1023 (ctx part), cols bid*4.. for 3 gates
    for (int k = tid; k < 1024; k += 256) {
        #pragma unroll
        for (int g = 0; g < 3; ++g) {
            float4 v = *(const float4*)(Wxd + (size_t)k * G3 + g * 1024 + bid * 4);
            *(float4*)&Wxds[k * 12 + g * 4] = v;
        }
    }
    __syncthreads();

    const int j4 = bid * 4 + wv;
    const float bz_rc = b_rec[j4], br_rc = b_rec[1024 + j4], bc_rc = b_rec[2048 + j4];

    for (int t = 0; t < TT; ++t) {
        const float* hsrc = (t == 0) ? hT : hdT;

        // ---- S1: q = dec_h @ W2 + b2 (4 q-cols per block) ----
        {
            const int cq = lane & 3;
            const int kp = (lane >> 2) & 7;
            const int rgq = (lane >> 5) | (wv << 1);
            const int qc = bid * 4 + cq;
            const float* hp = hsrc + kp * 32 + rgq * 4;
            const float* wp = W2 + (size_t)kp * UU + qc;
            float a0 = 0, a1 = 0, a2 = 0, a3 = 0;
            for (int g = 0; g < 16; ++g) {
                float4 hv[8]; float wr[8];
                #pragma unroll
                for (int u = 0; u < 8; ++u) {
                    hv[u] = *(const float4*)(hp + (g * 8 + u) * 256);
                    wr[u] = wp[(size_t)(g * 8 + u) * 8 * UU];
                }
                #pragma unroll
                for (int u = 0; u < 8; ++u) {
                    a0 += hv[u].x * wr[u]; a1 += hv[u].y * wr[u];
                    a2 += hv[u].z * wr[u]; a3 += hv[u].w * wr[u];
                }
            }
            #pragma unroll
            for (int m = 4; m <= 16; m <<= 1) {
                a0 += __shfl_xor(a0, m, 64); a1 += __shfl_xor(a1, m, 64);
                a2 += __shfl_xor(a2, m, 64); a3 += __shfl_xor(a3, m, 64);
            }
            if (((lane >> 2) & 7) == 0) {
                float bb2 = b2[qc];
                q[(size_t)(rgq * 4 + 0) * UU + qc] = a0 + bb2;
                q[(size_t)(rgq * 4 + 1) * UU + qc] = a1 + bb2;
                q[(size_t)(rgq * 4 + 2) * UU + qc] = a2 + bb2;
                q[(size_t)(rgq * 4 + 3) * UU + qc] = a3 + bb2;
            }
        }
        grid_barrier(bar);

        // ---- S2: scores e[b][s] = tanh(pre_enc + q) . Va + bv ----
        {
            const int b = bid >> 3, s0 = (bid & 7) * 8;
            const int pi = tid >> 5, kq = tid & 31;
            const int srow = s0 + pi;
            const float* pe = pre + ((size_t)b * SS + srow) * UU;
            const float* qb = q + (size_t)b * UU;
            float acc = 0;
            #pragma unroll
            for (int kk = 0; kk < 8; ++kk) {
                int k = kq * 32 + kk * 4;
                float4 p4 = *(const float4*)(pe + k);
                float4 q4 = *(const float4*)(qb + k);
                float4 v4 = *(const float4*)(Va + k);
                acc += tanhf(p4.x + q4.x) * v4.x + tanhf(p4.y + q4.y) * v4.y +
                       tanhf(p4.z + q4.z) * v4.z + tanhf(p4.w + q4.w) * v4.w;
            }
            #pragma unroll
            for (int m = 16; m >= 1; m >>= 1) acc += __shfl_xor(acc, m, 32);
            if (kq == 0) esc[b * SS + srow] = acc + bv[0];
        }
        grid_barrier(bar);

        // ---- S3: softmax + ctx (coalesced over U) into xT ----
        {
            const int b = bid >> 3, ug = bid & 7;
            if (tid < 64) eL[tid] = esc[b * SS + tid];
            __syncthreads();
            if (tid < 64) {
                float v = eL[tid];
                float m = v;
                #pragma unroll
                for (int mm = 32; mm >= 1; mm >>= 1) m = fmaxf(m, __shfl_xor(m, mm, 64));
                float p = expf(v - m);
                float sum = p;
                #pragma unroll
                for (int mm = 32; mm >= 1; mm >>= 1) sum += __shfl_xor(sum, mm, 64);
                attnL[tid] = p / sum;
            }
            __syncthreads();
            const int u = ug * 128 + (tid & 127), sp = tid >> 7;
            float acc = 0;
            #pragma unroll 8
            for (int i = 0; i < 32; ++i) {
                int srow = sp * 32 + i;
                acc += attnL[srow] * enc[((size_t)b * SS + srow) * UU + u];
            }
            shs[(tid & 127) * 2 + sp] = acc;
            __syncthreads();
            if (tid < 128) xT[(size_t)(ug * 128 + tid) * BB + b] = shs[tid * 2] + shs[tid * 2 + 1];
        }
        grid_barrier(bar);

        // ---- S4: gx = ctx @ Wxd_top (+ GXd), gates with gh = b_rec, h_new ----
        {
            const int kp = lane & 7;
            const int rg = lane >> 3;
            float sz[4] = {0.f, 0.f, 0.f, 0.f};
            float sr[4] = {0.f, 0.f, 0.f, 0.f};
            float sc[4] = {0.f, 0.f, 0.f, 0.f};
            const float* xp = xT + kp * 32 + rg * 4;
            float4 cbuf[8], nbuf[8];
            #pragma unroll
            for (int u = 0; u < 8; ++u) cbuf[u] = *(const float4*)(xp + u * 256);
            #pragma unroll
            for (int g = 0; g < 16; ++g) {
                if (g < 15) {
                    #pragma unroll
                    for (int u = 0; u < 8; ++u)
                        nbuf[u] = *(const float4*)(xp + ((g + 1) * 8 + u) * 256);
                }
                #pragma unroll
                for (int u = 0; u < 8; ++u) {
                    int k = kp + 8 * (g * 8 + u);
                    float w0 = Wxds[k * 12 + wv];
                    float w1 = Wxds[k * 12 + 4 + wv];
                    float w2 = Wxds[k * 12 + 8 + wv];
                    float4 v = cbuf[u];
                    sz[0] += v.x * w0; sz[1] += v.y * w0; sz[2] += v.z * w0; sz[3] += v.w * w0;
                    sr[0] += v.x * w1; sr[1] += v.y * w1; sr[2] += v.z * w1; sr[3] += v.w * w1;
                    sc[0] += v.x * w2; sc[1] += v.y * w2; sc[2] += v.z * w2; sc[3] += v.w * w2;
                }
                if (g < 15) {
                    #pragma unroll
                    for (int u = 0; u < 8; ++u) cbuf[u] = nbuf[u];
                }
            }
            #pragma unroll
            for (int m = 1; m <= 4; m <<= 1) {
                #pragma unroll
                for (int i = 0; i < 4; ++i) {
                    sz[i] += __shfl_xor(sz[i], m, 64);
                    sr[i] += __shfl_xor(sr[i], m, 64);
                    sc[i] += __shfl_xor(sc[i], m, 64);
                }
            }
            if (kp == 0) {
                #pragma unroll
                for (int i = 0; i < 4; ++i) {
                    int r = rg * 4 + i;
                    const float* gx = GXd + (size_t)(t * BB + r) * G3;
                    float xz = sz[i] + gx[j4];
                    float xr = sr[i] + gx[1024 + j4];
                    float xc = sc[i] + gx[2048 + j4];
                    float z = sigmoidf_(xz + bz_rc);
                    float rr = sigmoidf_(xr + br_rc);
                    float cc = tanhf(xc + rr * bc_rc);
                    float h = (1.0f - z) * cc;       // z*h0 + (1-z)*c, h0 = 0
                    Hd[((size_t)r * TT + t) * UU + j4] = h;
                    hdT[(size_t)j4 * BB + r] = h;
                }
            }
        }
        grid_barrier(bar);
    }
}

// ---------------- argmax with numpy first-index tie-break ----------------
__global__ __launch_bounds__(256) void k_argmax(const float* __restrict__ logits,
                                                float* __restrict__ outp) {
    const int row = blockIdx.x;
    const float* lr = logits + (size_t)row * VV;
    const int tid = threadIdx.x;
    float best = -INFINITY;
    int bidx = 0x7fffffff;
    for (int c = tid; c < VV; c += 256) {
        float v = lr[c];
        if (v > best) { best = v; bidx = c; }
    }
    __shared__ float bv_[256];
    __shared__ int bi_[256];
    bv_[tid] = best; bi_[tid] = bidx;
    __syncthreads();
    for (int s2 = 128; s2 > 0; s2 >>= 1) {
        if (tid < s2) {
            float ov = bv_[tid + s2]; int oi = bi_[tid + s2];
            if (ov > bv_[tid] || (ov == bv_[tid] && oi < bi_[tid])) {
                bv_[tid] = ov; bi_[tid] = oi;
            }
        }
        __syncthreads();
    }
    if (tid == 0) outp[row] = (float)bi_[0];
}

extern "C" void kernel_launch(void* const* d_in, const int* in_sizes, int n_in,
                              void* d_out, int out_size, void* d_ws, size_t ws_size,
                              hipStream_t stream) {
    const int* enc_in = (const int*)d_in[0];
    const int* teacher = (const int*)d_in[1];
    const float* Ee = (const float*)d_in[4];
    const float* eWx = (const float*)d_in[5];
    const float* eWh = (const float*)d_in[6];
    const float* eb_in = (const float*)d_in[7];
    const float* eb_rec = (const float*)d_in[8];
    const float* Ed = (const float*)d_in[9];
    const float* dWx = (const float*)d_in[10];
    // d_in[11] dec_Wh structurally unused: h0_dec == 0 -> gh == b_rec
    const float* db_in = (const float*)d_in[12];
    const float* db_rec = (const float*)d_in[13];
    const float* W1 = (const float*)d_in[14];
    const float* b1 = (const float*)d_in[15];
    const float* W2 = (const float*)d_in[16];
    const float* b2 = (const float*)d_in[17];
    const float* Va = (const float*)d_in[18];
    const float* bvv = (const float*)d_in[19];
    const float* Wf = (const float*)d_in[20];
    const float* bf = (const float*)d_in[21];
    float* ws = (float*)d_ws;
    float* out = (float*)d_out;

    // prep: XembT gather + hT slot0 zero + Demb gather + barrier zero
    const int NTOT = SS * EE * BB + UU * BB + BB * TT * EE + 16;
    k_prep<<<dim3((NTOT + 255) / 256), dim3(256), 0, stream>>>(enc_in, Ee, teacher, Ed, ws);

    // GXd = Demb @ dec_Wx[1024:1280,:] + dec_b_in : [512,256]x[256,3072]
    k_gemm<<<dim3(8, 24), dim3(256), 0, stream>>>(ws + WS_DEMB, dWx + (size_t)UU * G3, db_in,
                                                  ws + WS_GXD, BB * TT, G3, EE);

    // encoder recurrence (persistent, 64 steps)
    k_encoder<<<dim3(NBLK), dim3(256), 0, stream>>>(eWh, eWx, eb_in, eb_rec, ws);

    // pre_enc = encoded @ W1 + b1 : [2048,1024]x[1024,1024]
    k_gemm<<<dim3(32, 8), dim3(256), 0, stream>>>(ws + WS_ENC, W1, b1, ws + WS_PRE, BB * SS, UU, UU);

    // decoder (persistent, 16 steps x 4 phases)
    k_decoder<<<dim3(NBLK), dim3(256), 0, stream>>>(W2, b2, Va, bvv, dWx, db_rec, ws);

    // logits = Hdec @ Wf + bf : [512,1024]x[1024,20200] -> d_out
    k_gemm<<<dim3(8, 158), dim3(256), 0, stream>>>(ws + WS_HD, Wf, bf, out, BB * TT, VV, UU);

    // predictions = argmax(logits)
    k_argmax<<<dim3(BB * TT), dim3(256), 0, stream>>>(out, out + (size_t)BB * TT * VV);
}

// Round 3
// 6068.703 us; speedup vs baseline: 1.5591x; 1.2244x over previous
//
#include <hip/hip_runtime.h>
#include <cmath>

#define BB 32
#define SS 64
#define TT 16
#define UU 1024
#define EE 256
#define VV 20200
#define G3 3072
#define NBLK 256

// workspace layout (float offsets)
#define WS_XEMBT 0                          // XembT [S][E][B]
#define WS_HT    (WS_XEMBT + SS*EE*BB)      // hT: 2 ping-pong slots of [U][B]
#define WS_ENC   (WS_HT + 2*UU*BB)          // encoded [(b*S+s)][U]
#define WS_PRE   (WS_ENC + BB*SS*UU)        // pre_enc [(b*S+s)][U]
#define WS_Q     (WS_PRE + BB*SS*UU)        // q [b][U]
#define WS_ESC   (WS_Q + BB*UU)             // scores [b][S]
#define WS_XT    (WS_ESC + BB*SS)           // ctx transposed [U][B]
#define WS_HDT   (WS_XT + UU*BB)            // dec hidden transposed [U][B]
#define WS_HD    (WS_HDT + UU*BB)           // Hdec [(b*T+t)][U]
#define WS_DEMB  (WS_HD + BB*TT*UU)         // Demb [(t*B+b)][E]
#define WS_GXD   (WS_DEMB + BB*TT*EE)       // GXd  [(t*B+b)][3U]  (emb@Wxd_bot + b_in)
#define WS_BAR   (WS_GXD + BB*TT*G3)        // barrier state (uints)

__device__ __forceinline__ float sigmoidf_(float x) {
    return 1.0f / (1.0f + expf(-x));
}

// sense-reversing grid barrier, device scope (256 blocks, all resident).
// KEY (round 3): RELEASE on arrival (one L2 writeback publishes our stores),
// RELAXED spin (agent-scope atomic loads bypass L2 WITHOUT invalidating it),
// single ACQUIRE fence on exit (one L1/L2 invalidate to see remote stores).
// Round-2's ACQUIRE-per-poll invalidated the per-XCD L2 continuously.
__device__ __forceinline__ void grid_barrier(unsigned* bar) {
    __syncthreads();
    if (threadIdx.x == 0) {
        unsigned* cnt = bar;
        unsigned* gen = bar + 1;
        unsigned g = __hip_atomic_load(gen, __ATOMIC_RELAXED, __HIP_MEMORY_SCOPE_AGENT);
        unsigned a = __hip_atomic_fetch_add(cnt, 1u, __ATOMIC_RELEASE, __HIP_MEMORY_SCOPE_AGENT);
        if (a == NBLK - 1u) {
            __hip_atomic_store(cnt, 0u, __ATOMIC_RELAXED, __HIP_MEMORY_SCOPE_AGENT);
            __hip_atomic_store(gen, g + 1u, __ATOMIC_RELEASE, __HIP_MEMORY_SCOPE_AGENT);
        } else {
            while (__hip_atomic_load(gen, __ATOMIC_RELAXED, __HIP_MEMORY_SCOPE_AGENT) == g) {
                __builtin_amdgcn_s_sleep(2);
            }
        }
        __builtin_amdgcn_fence(__ATOMIC_ACQUIRE, "agent");
    }
    __syncthreads();
}

// ---------------- prep: gathers + zero init ----------------
__global__ __launch_bounds__(256) void k_prep(const int* __restrict__ enc_in,
                                              const float* __restrict__ Ee,
                                              const int* __restrict__ teacher,
                                              const float* __restrict__ Ed,
                                              float* __restrict__ ws) {
    int gid = blockIdx.x * 256 + threadIdx.x;
    const int NE = SS * EE * BB;               // 524288
    const int NH = UU * BB;                    // 32768
    const int ND = BB * TT * EE;               // 131072
    if (gid < NE) {
        int b = gid & 31;
        int e = (gid >> 5) & 255;
        int s = gid >> 13;
        ws[WS_XEMBT + gid] = Ee[(size_t)enc_in[b * SS + s] * EE + e];
    } else if (gid < NE + NH) {
        ws[WS_HT + (gid - NE)] = 0.0f;         // h(-1) = 0 (slot 0)
    } else if (gid < NE + NH + ND) {
        int idx = gid - NE - NH;
        int e = idx & 255;
        int row = idx >> 8;                     // t*32 + b
        int t = row >> 5, b = row & 31;
        ws[WS_DEMB + idx] = Ed[(size_t)teacher[b * TT + t] * EE + e];
    } else if (gid < NE + NH + ND + 16) {
        ((unsigned*)(ws + WS_BAR))[gid - NE - NH - ND] = 0u;
    }
}

// ---------------- encoder: 64 GRU steps, persistent grid, weights in LDS ----------------
// 256 thr = 4 waves; wave wv owns gate-col j = bid*4+wv. lane: kp=lane&7 (split-K in-wave),
// rg=lane>>3 (4 batch rows each). k interleaved: k = kp + 8*kk -> 1KB-coalesced h loads.
// 16-deep float4 prefetch (1 wave/SIMD -> VGPRs free; launch_bounds(...,1)).
__global__ __launch_bounds__(256, 1) void k_encoder(const float* __restrict__ Wh,
                                                    const float* __restrict__ Wx,
                                                    const float* __restrict__ b_in,
                                                    const float* __restrict__ b_rec,
                                                    float* __restrict__ ws) {
    float* XembT = ws + WS_XEMBT;
    float* hT = ws + WS_HT;
    float* enc = ws + WS_ENC;
    unsigned* bar = (unsigned*)(ws + WS_BAR);

    __shared__ float Whs[12288];   // [k][12] : 3 gates x 4 cols
    __shared__ float Wxs[3072];

    const int tid = threadIdx.x;
    const int bid = blockIdx.x;
    const int wv = tid >> 6;
    const int lane = tid & 63;
    const int kp = lane & 7;
    const int rg = lane >> 3;
    const int j = bid * 4 + wv;

    for (int k = tid; k < 1024; k += 256) {
        #pragma unroll
        for (int g = 0; g < 3; ++g) {
            float4 v = *(const float4*)(Wh + (size_t)k * G3 + g * 1024 + bid * 4);
            *(float4*)&Whs[k * 12 + g * 4] = v;
        }
    }
    if (tid < 256) {
        int k = tid;
        #pragma unroll
        for (int g = 0; g < 3; ++g) {
            float4 v = *(const float4*)(Wx + (size_t)k * G3 + g * 1024 + bid * 4);
            *(float4*)&Wxs[k * 12 + g * 4] = v;
        }
    }
    __syncthreads();

    const float bz_in = b_in[j], br_in = b_in[1024 + j], bc_in = b_in[2048 + j];
    const float bz_rc = b_rec[j], br_rc = b_rec[1024 + j], bc_rc = b_rec[2048 + j];

    for (int t = 0; t < SS; ++t) {
        const float* hprev = hT + (t & 1) * (UU * BB);
        float* hnext = hT + ((t & 1) ^ 1) * (UU * BB);

        float az[4] = {0.f, 0.f, 0.f, 0.f};
        float arr[4] = {0.f, 0.f, 0.f, 0.f};
        float ahh[4] = {0.f, 0.f, 0.f, 0.f};
        float axh[4] = {0.f, 0.f, 0.f, 0.f};

        // ---- h @ Wh : K=1024, 128 k per thread, 16-deep rotated prefetch ----
        {
            const float* hp = hprev + kp * 32 + rg * 4;
            float4 cbuf[16], nbuf[16];
            #pragma unroll
            for (int u = 0; u < 16; ++u) cbuf[u] = *(const float4*)(hp + u * 256);
            #pragma unroll
            for (int g = 0; g < 8; ++g) {
                if (g < 7) {
                    #pragma unroll
                    for (int u = 0; u < 16; ++u)
                        nbuf[u] = *(const float4*)(hp + ((g + 1) * 16 + u) * 256);
                }
                #pragma unroll
                for (int u = 0; u < 16; ++u) {
                    int k = kp + 8 * (g * 16 + u);
                    float w0 = Whs[k * 12 + wv];
                    float w1 = Whs[k * 12 + 4 + wv];
                    float w2 = Whs[k * 12 + 8 + wv];
                    float4 hv = cbuf[u];
                    az[0] += hv.x * w0; az[1] += hv.y * w0; az[2] += hv.z * w0; az[3] += hv.w * w0;
                    arr[0] += hv.x * w1; arr[1] += hv.y * w1; arr[2] += hv.z * w1; arr[3] += hv.w * w1;
                    ahh[0] += hv.x * w2; ahh[1] += hv.y * w2; ahh[2] += hv.z * w2; ahh[3] += hv.w * w2;
                }
                if (g < 7) {
                    #pragma unroll
                    for (int u = 0; u < 16; ++u) cbuf[u] = nbuf[u];
                }
            }
        }
        // ---- x @ Wx : K=256, 32 k per thread, 2 groups of 16 ----
        {
            const float* xp = XembT + t * (EE * BB) + kp * 32 + rg * 4;
            #pragma unroll
            for (int g = 0; g < 2; ++g) {
                float4 xv[16];
                #pragma unroll
                for (int u = 0; u < 16; ++u) xv[u] = *(const float4*)(xp + (g * 16 + u) * 256);
                #pragma unroll
                for (int u = 0; u < 16; ++u) {
                    int k = kp + 8 * (g * 16 + u);
                    float w0 = Wxs[k * 12 + wv];
                    float w1 = Wxs[k * 12 + 4 + wv];
                    float w2 = Wxs[k * 12 + 8 + wv];
                    float4 v = xv[u];
                    az[0] += v.x * w0; az[1] += v.y * w0; az[2] += v.z * w0; az[3] += v.w * w0;
                    arr[0] += v.x * w1; arr[1] += v.y * w1; arr[2] += v.z * w1; arr[3] += v.w * w1;
                    axh[0] += v.x * w2; axh[1] += v.y * w2; axh[2] += v.z * w2; axh[3] += v.w * w2;
                }
            }
        }
        // ---- in-wave split-K reduce (kp lives in lane bits 0..2) ----
        #pragma unroll
        for (int m = 1; m <= 4; m <<= 1) {
            #pragma unroll
            for (int i = 0; i < 4; ++i) {
                az[i] += __shfl_xor(az[i], m, 64);
                arr[i] += __shfl_xor(arr[i], m, 64);
                ahh[i] += __shfl_xor(ahh[i], m, 64);
                axh[i] += __shfl_xor(axh[i], m, 64);
            }
        }
        if (kp == 0) {
            #pragma unroll
            for (int i = 0; i < 4; ++i) {
                int r = rg * 4 + i;
                float z = sigmoidf_(az[i] + bz_in + bz_rc);
                float rr = sigmoidf_(arr[i] + br_in + br_rc);
                float cc = tanhf(axh[i] + bc_in + rr * (ahh[i] + bc_rc));
                float hold = hprev[j * 32 + r];
                float hnew = z * hold + (1.0f - z) * cc;
                hnext[j * 32 + r] = hnew;
                enc[((size_t)r * SS + t) * UU + j] = hnew;
            }
        }
        grid_barrier(bar);
    }
}

// ---------------- generic fp32 GEMM: C[M,N] = A[M,K]@B[K,N] + bias ----------------
__global__ __launch_bounds__(256) void k_gemm(const float* __restrict__ A,
                                              const float* __restrict__ Bm,
                                              const float* __restrict__ bias,
                                              float* __restrict__ C,
                                              int M, int N, int K) {
    __shared__ float As[16][68];
    __shared__ float Bs[16][132];
    const int rb = blockIdx.x * 64;
    const int cb = blockIdx.y * 128;
    const int tid = threadIdx.x;
    const int cg = tid & 31;
    const int rg = tid >> 5;
    float acc[8][4] = {{0.f}};

    const int arow = tid >> 2, akq = (tid & 3) * 4;
    const int bkk = tid >> 4, bc8 = (tid & 15) * 8;
    const bool nfull = (cb + 128 <= N);

    for (int k0 = 0; k0 < K; k0 += 16) {
        {
            float4 a4 = *(const float4*)(A + (size_t)(rb + arow) * K + k0 + akq);
            As[akq + 0][arow] = a4.x; As[akq + 1][arow] = a4.y;
            As[akq + 2][arow] = a4.z; As[akq + 3][arow] = a4.w;
        }
        {
            int col = cb + bc8;
            const float* bp = Bm + (size_t)(k0 + bkk) * N + col;
            if (nfull) {
                float4 x0 = *(const float4*)bp;
                float4 x1 = *(const float4*)(bp + 4);
                Bs[bkk][bc8 + 0] = x0.x; Bs[bkk][bc8 + 1] = x0.y; Bs[bkk][bc8 + 2] = x0.z; Bs[bkk][bc8 + 3] = x0.w;
                Bs[bkk][bc8 + 4] = x1.x; Bs[bkk][bc8 + 5] = x1.y; Bs[bkk][bc8 + 6] = x1.z; Bs[bkk][bc8 + 7] = x1.w;
            } else {
                #pragma unroll
                for (int jj = 0; jj < 8; ++jj)
                    Bs[bkk][bc8 + jj] = (col + jj < N) ? bp[jj] : 0.0f;
            }
        }
        __syncthreads();
        #pragma unroll
        for (int kk = 0; kk < 16; ++kk) {
            float4 a0 = *(const float4*)&As[kk][rg * 8];
            float4 a1 = *(const float4*)&As[kk][rg * 8 + 4];
            float4 b0 = *(const float4*)&Bs[kk][cg * 4];
            float av[8] = {a0.x, a0.y, a0.z, a0.w, a1.x, a1.y, a1.z, a1.w};
            float bv[4] = {b0.x, b0.y, b0.z, b0.w};
            #pragma unroll
            for (int i = 0; i < 8; ++i)
                #pragma unroll
                for (int jj = 0; jj < 4; ++jj)
                    acc[i][jj] += av[i] * bv[jj];
        }
        __syncthreads();
    }
    const int col0 = cb + cg * 4;
    const bool cfull = (col0 + 4 <= N);
    #pragma unroll
    for (int i = 0; i < 8; ++i) {
        int row = rb + rg * 8 + i;
        float* cp = C + (size_t)row * N + col0;
        if (cfull) {
            float4 o;
            o.x = acc[i][0] + bias[col0 + 0];
            o.y = acc[i][1] + bias[col0 + 1];
            o.z = acc[i][2] + bias[col0 + 2];
            o.w = acc[i][3] + bias[col0 + 3];
            *(float4*)cp = o;
        } else {
            #pragma unroll
            for (int jj = 0; jj < 4; ++jj)
                if (col0 + jj < N) cp[jj] = acc[i][jj] + bias[col0 + jj];
        }
    }
}

// ---------------- decoder: 16 steps x 4 phases, persistent grid ----------------
__global__ __launch_bounds__(256, 1) void k_decoder(const float* __restrict__ W2,
                                                    const float* __restrict__ b2,
                                                    const float* __restrict__ Va,
                                                    const float* __restrict__ bv,
                                                    const float* __restrict__ Wxd,
                                                    const float* __restrict__ b_rec,
                                                    float* __restrict__ ws) {
    float* hT = ws + WS_HT;            // slot 0 = encoder final hidden
    float* enc = ws + WS_ENC;
    float* pre = ws + WS_PRE;
    float* q = ws + WS_Q;
    float* esc = ws + WS_ESC;
    float* xT = ws + WS_XT;
    float* hdT = ws + WS_HDT;
    float* Hd = ws + WS_HD;
    float* GXd = ws + WS_GXD;
    unsigned* bar = (unsigned*)(ws + WS_BAR) + 2;

    __shared__ float Wxds[12288];      // ctx-part weight tile [k][12]
    __shared__ float eL[64];
    __shared__ float attnL[64];
    __shared__ float shs[256];

    const int tid = threadIdx.x;
    const int bid = blockIdx.x;
    const int wv = tid >> 6;
    const int lane = tid & 63;

    for (int k = tid; k < 1024; k += 256) {
        #pragma unroll
        for (int g = 0; g < 3; ++g) {
            float4 v = *(const float4*)(Wxd + (size_t)k * G3 + g * 1024 + bid * 4);
            *(float4*)&Wxds[k * 12 + g * 4] = v;
        }
    }
    __syncthreads();

    const int j4 = bid * 4 + wv;
    const float bz_rc = b_rec[j4], br_rc = b_rec[1024 + j4], bc_rc = b_rec[2048 + j4];

    for (int t = 0; t < TT; ++t) {
        const float* hsrc = (t == 0) ? hT : hdT;

        // ---- S1: q = dec_h @ W2 + b2 (4 q-cols per block) ----
        {
            const int cq = lane & 3;
            const int kp = (lane >> 2) & 7;
            const int rgq = (lane >> 5) | (wv << 1);
            const int qc = bid * 4 + cq;
            const float* hp = hsrc + kp * 32 + rgq * 4;
            const float* wp = W2 + (size_t)kp * UU + qc;
            float a0 = 0, a1 = 0, a2 = 0, a3 = 0;
            for (int g = 0; g < 16; ++g) {
                float4 hv[8]; float wr[8];
                #pragma unroll
                for (int u = 0; u < 8; ++u) {
                    hv[u] = *(const float4*)(hp + (g * 8 + u) * 256);
                    wr[u] = wp[(size_t)(g * 8 + u) * 8 * UU];
                }
                #pragma unroll
                for (int u = 0; u < 8; ++u) {
                    a0 += hv[u].x * wr[u]; a1 += hv[u].y * wr[u];
                    a2 += hv[u].z * wr[u]; a3 += hv[u].w * wr[u];
                }
            }
            #pragma unroll
            for (int m = 4; m <= 16; m <<= 1) {
                a0 += __shfl_xor(a0, m, 64); a1 += __shfl_xor(a1, m, 64);
                a2 += __shfl_xor(a2, m, 64); a3 += __shfl_xor(a3, m, 64);
            }
            if (((lane >> 2) & 7) == 0) {
                float bb2 = b2[qc];
                q[(size_t)(rgq * 4 + 0) * UU + qc] = a0 + bb2;
                q[(size_t)(rgq * 4 + 1) * UU + qc] = a1 + bb2;
                q[(size_t)(rgq * 4 + 2) * UU + qc] = a2 + bb2;
                q[(size_t)(rgq * 4 + 3) * UU + qc] = a3 + bb2;
            }
        }
        grid_barrier(bar);

        // ---- S2: scores e[b][s] = tanh(pre_enc + q) . Va + bv ----
        {
            const int b = bid >> 3, s0 = (bid & 7) * 8;
            const int pi = tid >> 5, kq = tid & 31;
            const int srow = s0 + pi;
            const float* pe = pre + ((size_t)b * SS + srow) * UU;
            const float* qb = q + (size_t)b * UU;
            float acc = 0;
            #pragma unroll
            for (int kk = 0; kk < 8; ++kk) {
                int k = kq * 32 + kk * 4;
                float4 p4 = *(const float4*)(pe + k);
                float4 q4 = *(const float4*)(qb + k);
                float4 v4 = *(const float4*)(Va + k);
                acc += tanhf(p4.x + q4.x) * v4.x + tanhf(p4.y + q4.y) * v4.y +
                       tanhf(p4.z + q4.z) * v4.z + tanhf(p4.w + q4.w) * v4.w;
            }
            #pragma unroll
            for (int m = 16; m >= 1; m >>= 1) acc += __shfl_xor(acc, m, 32);
            if (kq == 0) esc[b * SS + srow] = acc + bv[0];
        }
        grid_barrier(bar);

        // ---- S3: softmax + ctx (coalesced over U) into xT ----
        {
            const int b = bid >> 3, ug = bid & 7;
            if (tid < 64) eL[tid] = esc[b * SS + tid];
            __syncthreads();
            if (tid < 64) {
                float v = eL[tid];
                float m = v;
                #pragma unroll
                for (int mm = 32; mm >= 1; mm >>= 1) m = fmaxf(m, __shfl_xor(m, mm, 64));
                float p = expf(v - m);
                float sum = p;
                #pragma unroll
                for (int mm = 32; mm >= 1; mm >>= 1) sum += __shfl_xor(sum, mm, 64);
                attnL[tid] = p / sum;
            }
            __syncthreads();
            const int u = ug * 128 + (tid & 127), sp = tid >> 7;
            float acc = 0;
            #pragma unroll 8
            for (int i = 0; i < 32; ++i) {
                int srow = sp * 32 + i;
                acc += attnL[srow] * enc[((size_t)b * SS + srow) * UU + u];
            }
            shs[(tid & 127) * 2 + sp] = acc;
            __syncthreads();
            if (tid < 128) xT[(size_t)(ug * 128 + tid) * BB + b] = shs[tid * 2] + shs[tid * 2 + 1];
        }
        grid_barrier(bar);

        // ---- S4: gx = ctx @ Wxd_top (+ GXd), gates with gh = b_rec, h_new ----
        {
            const int kp = lane & 7;
            const int rg = lane >> 3;
            float sz[4] = {0.f, 0.f, 0.f, 0.f};
            float sr[4] = {0.f, 0.f, 0.f, 0.f};
            float sc[4] = {0.f, 0.f, 0.f, 0.f};
            const float* xp = xT + kp * 32 + rg * 4;
            float4 cbuf[16], nbuf[16];
            #pragma unroll
            for (int u = 0; u < 16; ++u) cbuf[u] = *(const float4*)(xp + u * 256);
            #pragma unroll
            for (int g = 0; g < 8; ++g) {
                if (g < 7) {
                    #pragma unroll
                    for (int u = 0; u < 16; ++u)
                        nbuf[u] = *(const float4*)(xp + ((g + 1) * 16 + u) * 256);
                }
                #pragma unroll
                for (int u = 0; u < 16; ++u) {
                    int k = kp + 8 * (g * 16 + u);
                    float w0 = Wxds[k * 12 + wv];
                    float w1 = Wxds[k * 12 + 4 + wv];
                    float w2 = Wxds[k * 12 + 8 + wv];
                    float4 v = cbuf[u];
                    sz[0] += v.x * w0; sz[1] += v.y * w0; sz[2] += v.z * w0; sz[3] += v.w * w0;
                    sr[0] += v.x * w1; sr[1] += v.y * w1; sr[2] += v.z * w1; sr[3] += v.w * w1;
                    sc[0] += v.x * w2; sc[1] += v.y * w2; sc[2] += v.z * w2; sc[3] += v.w * w2;
                }
                if (g < 7) {
                    #pragma unroll
                    for (int u = 0; u < 16; ++u) cbuf[u] = nbuf[u];
                }
            }
            #pragma unroll
            for (int m = 1; m <= 4; m <<= 1) {
                #pragma unroll
                for (int i = 0; i < 4; ++i) {
                    sz[i] += __shfl_xor(sz[i], m, 64);
                    sr[i] += __shfl_xor(sr[i], m, 64);
                    sc[i] += __shfl_xor(sc[i], m, 64);
                }
            }
            if (kp == 0) {
                #pragma unroll
                for (int i = 0; i < 4; ++i) {
                    int r = rg * 4 + i;
                    const float* gx = GXd + (size_t)(t * BB + r) * G3;
                    float xz = sz[i] + gx[j4];
                    float xr = sr[i] + gx[1024 + j4];
                    float xc = sc[i] + gx[2048 + j4];
                    float z = sigmoidf_(xz + bz_rc);
                    float rr = sigmoidf_(xr + br_rc);
                    float cc = tanhf(xc + rr * bc_rc);
                    float h = (1.0f - z) * cc;       // z*h0 + (1-z)*c, h0 = 0
                    Hd[((size_t)r * TT + t) * UU + j4] = h;
                    hdT[(size_t)j4 * BB + r] = h;
                }
            }
        }
        grid_barrier(bar);
    }
}

// ---------------- argmax with numpy first-index tie-break ----------------
__global__ __launch_bounds__(256) void k_argmax(const float* __restrict__ logits,
                                                float* __restrict__ outp) {
    const int row = blockIdx.x;
    const float* lr = logits + (size_t)row * VV;
    const int tid = threadIdx.x;
    float best = -INFINITY;
    int bidx = 0x7fffffff;
    for (int c = tid; c < VV; c += 256) {
        float v = lr[c];
        if (v > best) { best = v; bidx = c; }
    }
    __shared__ float bv_[256];
    __shared__ int bi_[256];
    bv_[tid] = best; bi_[tid] = bidx;
    __syncthreads();
    for (int s2 = 128; s2 > 0; s2 >>= 1) {
        if (tid < s2) {
            float ov = bv_[tid + s2]; int oi = bi_[tid + s2];
            if (ov > bv_[tid] || (ov == bv_[tid] && oi < bi_[tid])) {
                bv_[tid] = ov; bi_[tid] = oi;
            }
        }
        __syncthreads();
    }
    if (tid == 0) outp[row] = (float)bi_[0];
}

extern "C" void kernel_launch(void* const* d_in, const int* in_sizes, int n_in,
                              void* d_out, int out_size, void* d_ws, size_t ws_size,
                              hipStream_t stream) {
    const int* enc_in = (const int*)d_in[0];
    const int* teacher = (const int*)d_in[1];
    const float* Ee = (const float*)d_in[4];
    const float* eWx = (const float*)d_in[5];
    const float* eWh = (const float*)d_in[6];
    const float* eb_in = (const float*)d_in[7];
    const float* eb_rec = (const float*)d_in[8];
    const float* Ed = (const float*)d_in[9];
    const float* dWx = (const float*)d_in[10];
    // d_in[11] dec_Wh structurally unused: h0_dec == 0 -> gh == b_rec
    const float* db_in = (const float*)d_in[12];
    const float* db_rec = (const float*)d_in[13];
    const float* W1 = (const float*)d_in[14];
    const float* b1 = (const float*)d_in[15];
    const float* W2 = (const float*)d_in[16];
    const float* b2 = (const float*)d_in[17];
    const float* Va = (const float*)d_in[18];
    const float* bvv = (const float*)d_in[19];
    const float* Wf = (const float*)d_in[20];
    const float* bf = (const float*)d_in[21];
    float* ws = (float*)d_ws;
    float* out = (float*)d_out;

    // prep: XembT gather + hT slot0 zero + Demb gather + barrier zero
    const int NTOT = SS * EE * BB + UU * BB + BB * TT * EE + 16;
    k_prep<<<dim3((NTOT + 255) / 256), dim3(256), 0, stream>>>(enc_in, Ee, teacher, Ed, ws);

    // GXd = Demb @ dec_Wx[1024:1280,:] + dec_b_in : [512,256]x[256,3072]
    k_gemm<<<dim3(8, 24), dim3(256), 0, stream>>>(ws + WS_DEMB, dWx + (size_t)UU * G3, db_in,
                                                  ws + WS_GXD, BB * TT, G3, EE);

    // encoder recurrence (persistent, 64 steps)
    k_encoder<<<dim3(NBLK), dim3(256), 0, stream>>>(eWh, eWx, eb_in, eb_rec, ws);

    // pre_enc = encoded @ W1 + b1 : [2048,1024]x[1024,1024]
    k_gemm<<<dim3(32, 8), dim3(256), 0, stream>>>(ws + WS_ENC, W1, b1, ws + WS_PRE, BB * SS, UU, UU);

    // decoder (persistent, 16 steps x 4 phases)
    k_decoder<<<dim3(NBLK), dim3(256), 0, stream>>>(W2, b2, Va, bvv, dWx, db_rec, ws);

    // logits = Hdec @ Wf + bf : [512,1024]x[1024,20200] -> d_out
    k_gemm<<<dim3(8, 158), dim3(256), 0, stream>>>(ws + WS_HD, Wf, bf, out, BB * TT, VV, UU);

    // predictions = argmax(logits)
    k_argmax<<<dim3(BB * TT), dim3(256), 0, stream>>>(out, out + (size_t)BB * TT * VV);
}

// Round 4
// 3688.678 us; speedup vs baseline: 2.5651x; 1.6452x over previous
//
#include <hip/hip_runtime.h>
#include <cmath>

#define BB 32
#define SS 64
#define TT 16
#define UU 1024
#define EE 256
#define VV 20200
#define G3 3072
#define NBLK 256

// workspace layout (float offsets)
#define WS_XEMBT 0                          // XembT [S][E][B]
#define WS_HT    (WS_XEMBT + SS*EE*BB)      // hT: 2 ping-pong slots of [U][B]
#define WS_ENC   (WS_HT + 2*UU*BB)          // encoded [(b*S+s)][U]
#define WS_PRE   (WS_ENC + BB*SS*UU)        // pre_enc [(b*S+s)][U]
#define WS_Q     (WS_PRE + BB*SS*UU)        // q [b][U]
#define WS_ESC   (WS_Q + BB*UU)             // scores [b][S]
#define WS_XT    (WS_ESC + BB*SS)           // ctx transposed [U][B]
#define WS_HDT   (WS_XT + UU*BB)            // dec hidden transposed [U][B]
#define WS_HD    (WS_HDT + UU*BB)           // Hdec [(b*T+t)][U]
#define WS_DEMB  (WS_HD + BB*TT*UU)         // Demb [(t*B+b)][E]
#define WS_GXD   (WS_DEMB + BB*TT*EE)       // GXd  [(t*B+b)][3U]
#define WS_BAR   (WS_GXD + BB*TT*G3)        // 3 barrier sets x 1024 uints

__device__ __forceinline__ float sigmoidf_(float x) {
    return 1.0f / (1.0f + expf(-x));
}

// write-through store to the coherence point (no dirty L2 line -> no wbl2 needed
// at the barrier). Readers refresh via one acquire-inv per barrier.
__device__ __forceinline__ void store_agent(float* p, float v) {
    __hip_atomic_store(p, v, __ATOMIC_RELAXED, __HIP_MEMORY_SCOPE_AGENT);
}

// Hierarchical grid barrier (256 blocks = 8 groups x 32), parity double-buffered.
// All atomics RELAXED (no per-block L2 writeback); visibility of data comes from
// store_agent() writes + s_waitcnt(0) before arrival + one acquire-inv on exit.
// Counter/gen words live on separate 128B lines; <=32 spinners per gen line.
__device__ __forceinline__ void grid_barrier(unsigned* base, int grp, unsigned g) {
    __syncthreads();
    if (threadIdx.x == 0) {
        const unsigned p = g & 1u;
        unsigned* cnt  = base + ((unsigned)grp * 2u + p) * 32u;
        unsigned* root = base + (16u + p) * 32u;
        unsigned* gen  = base + (18u + (unsigned)grp) * 32u;
        __builtin_amdgcn_s_waitcnt(0);   // all prior agent stores completed at LLC
        bool done = false;
        unsigned a = __hip_atomic_fetch_add(cnt, 1u, __ATOMIC_RELAXED, __HIP_MEMORY_SCOPE_AGENT);
        if (a == 31u) {
            __hip_atomic_store(cnt, 0u, __ATOMIC_RELAXED, __HIP_MEMORY_SCOPE_AGENT);
            unsigned r = __hip_atomic_fetch_add(root, 1u, __ATOMIC_RELAXED, __HIP_MEMORY_SCOPE_AGENT);
            if (r == 7u) {
                __hip_atomic_store(root, 0u, __ATOMIC_RELAXED, __HIP_MEMORY_SCOPE_AGENT);
                #pragma unroll
                for (unsigned gg = 0; gg < 8; ++gg)
                    __hip_atomic_store(base + (18u + gg) * 32u, g + 1u,
                                       __ATOMIC_RELAXED, __HIP_MEMORY_SCOPE_AGENT);
                done = true;
            }
        }
        if (!done) {
            while (__hip_atomic_load(gen, __ATOMIC_RELAXED, __HIP_MEMORY_SCOPE_AGENT) <= g) {
                __builtin_amdgcn_s_sleep(4);
            }
        }
        __builtin_amdgcn_fence(__ATOMIC_ACQUIRE, "agent");   // one inv: see remote stores
    }
    __syncthreads();
}

// ---------------- diagnostic: 64 empty barriers (dur_us/64 = barrier cost) ----------------
__global__ __launch_bounds__(256, 1) void k_bartest(float* __restrict__ ws) {
    unsigned* base = (unsigned*)(ws + WS_BAR) + 2048;
    const int grp = blockIdx.x & 7;
    for (unsigned g = 0; g < 64; ++g) grid_barrier(base, grp, g);
}

// ---------------- prep: gathers + zero init ----------------
__global__ __launch_bounds__(256) void k_prep(const int* __restrict__ enc_in,
                                              const float* __restrict__ Ee,
                                              const int* __restrict__ teacher,
                                              const float* __restrict__ Ed,
                                              float* __restrict__ ws) {
    int gid = blockIdx.x * 256 + threadIdx.x;
    const int NE = SS * EE * BB;               // 524288
    const int NH = UU * BB;                    // 32768
    const int ND = BB * TT * EE;               // 131072
    if (gid < NE) {
        int b = gid & 31;
        int e = (gid >> 5) & 255;
        int s = gid >> 13;
        ws[WS_XEMBT + gid] = Ee[(size_t)enc_in[b * SS + s] * EE + e];
    } else if (gid < NE + NH) {
        ws[WS_HT + (gid - NE)] = 0.0f;         // h(-1) = 0 (slot 0)
    } else if (gid < NE + NH + ND) {
        int idx = gid - NE - NH;
        int e = idx & 255;
        int row = idx >> 8;                     // t*32 + b
        int t = row >> 5, b = row & 31;
        ws[WS_DEMB + idx] = Ed[(size_t)teacher[b * TT + t] * EE + e];
    } else if (gid < NE + NH + ND + 3072) {
        ((unsigned*)(ws + WS_BAR))[gid - NE - NH - ND] = 0u;
    }
}

// ---------------- encoder: 64 GRU steps, persistent grid, weights in LDS ----------------
// Wave wv owns gate-col j = bid*4+wv; lane: kp=lane&7 (split-K), rg=lane>>3 (4 batch rows).
// LDS weights packed [wv][k][4] -> one ds_read_b128 per k (z,r,c weights).
__global__ __launch_bounds__(256, 1) void k_encoder(const float* __restrict__ Wh,
                                                    const float* __restrict__ Wx,
                                                    const float* __restrict__ b_in,
                                                    const float* __restrict__ b_rec,
                                                    float* __restrict__ ws) {
    float* XembT = ws + WS_XEMBT;
    float* hT = ws + WS_HT;
    float* enc = ws + WS_ENC;
    unsigned* bar = (unsigned*)(ws + WS_BAR);

    __shared__ float Whs[16384];   // [wv][k][4]
    __shared__ float Wxs[4096];    // [wv][k][4]

    const int tid = threadIdx.x;
    const int bid = blockIdx.x;
    const int grp = bid & 7;
    const int wv = tid >> 6;
    const int lane = tid & 63;
    const int kp = lane & 7;
    const int rg = lane >> 3;
    const int j = bid * 4 + wv;

    for (int k = tid; k < 1024; k += 256) {
        #pragma unroll
        for (int g = 0; g < 3; ++g) {
            float4 v = *(const float4*)(Wh + (size_t)k * G3 + g * 1024 + bid * 4);
            Whs[0 * 4096 + k * 4 + g] = v.x;
            Whs[1 * 4096 + k * 4 + g] = v.y;
            Whs[2 * 4096 + k * 4 + g] = v.z;
            Whs[3 * 4096 + k * 4 + g] = v.w;
        }
    }
    if (tid < 256) {
        int k = tid;
        #pragma unroll
        for (int g = 0; g < 3; ++g) {
            float4 v = *(const float4*)(Wx + (size_t)k * G3 + g * 1024 + bid * 4);
            Wxs[0 * 1024 + k * 4 + g] = v.x;
            Wxs[1 * 1024 + k * 4 + g] = v.y;
            Wxs[2 * 1024 + k * 4 + g] = v.z;
            Wxs[3 * 1024 + k * 4 + g] = v.w;
        }
    }
    __syncthreads();

    const float* whb = Whs + wv * 4096;
    const float* wxb = Wxs + wv * 1024;
    const float bz_in = b_in[j], br_in = b_in[1024 + j], bc_in = b_in[2048 + j];
    const float bz_rc = b_rec[j], br_rc = b_rec[1024 + j], bc_rc = b_rec[2048 + j];

    for (int t = 0; t < SS; ++t) {
        const float* hprev = hT + (t & 1) * (UU * BB);
        float* hnext = hT + ((t & 1) ^ 1) * (UU * BB);

        float az[4] = {0.f, 0.f, 0.f, 0.f};
        float arr[4] = {0.f, 0.f, 0.f, 0.f};
        float ahh[4] = {0.f, 0.f, 0.f, 0.f};
        float axh[4] = {0.f, 0.f, 0.f, 0.f};

        // ---- h @ Wh : K=1024, 128 k per thread, 16-deep rotated prefetch ----
        {
            const float* hp = hprev + kp * 32 + rg * 4;
            float4 cbuf[16], nbuf[16];
            #pragma unroll
            for (int u = 0; u < 16; ++u) cbuf[u] = *(const float4*)(hp + u * 256);
            #pragma unroll
            for (int g = 0; g < 8; ++g) {
                if (g < 7) {
                    #pragma unroll
                    for (int u = 0; u < 16; ++u)
                        nbuf[u] = *(const float4*)(hp + ((g + 1) * 16 + u) * 256);
                }
                #pragma unroll
                for (int u = 0; u < 16; ++u) {
                    int k = kp + 8 * (g * 16 + u);
                    float4 w = *(const float4*)(whb + k * 4);
                    float4 hv = cbuf[u];
                    az[0] += hv.x * w.x; az[1] += hv.y * w.x; az[2] += hv.z * w.x; az[3] += hv.w * w.x;
                    arr[0] += hv.x * w.y; arr[1] += hv.y * w.y; arr[2] += hv.z * w.y; arr[3] += hv.w * w.y;
                    ahh[0] += hv.x * w.z; ahh[1] += hv.y * w.z; ahh[2] += hv.z * w.z; ahh[3] += hv.w * w.z;
                }
                if (g < 7) {
                    #pragma unroll
                    for (int u = 0; u < 16; ++u) cbuf[u] = nbuf[u];
                }
            }
        }
        // ---- x @ Wx : K=256, 32 k per thread ----
        {
            const float* xp = XembT + t * (EE * BB) + kp * 32 + rg * 4;
            #pragma unroll
            for (int g = 0; g < 2; ++g) {
                float4 xv[16];
                #pragma unroll
                for (int u = 0; u < 16; ++u) xv[u] = *(const float4*)(xp + (g * 16 + u) * 256);
                #pragma unroll
                for (int u = 0; u < 16; ++u) {
                    int k = kp + 8 * (g * 16 + u);
                    float4 w = *(const float4*)(wxb + k * 4);
                    float4 v = xv[u];
                    az[0] += v.x * w.x; az[1] += v.y * w.x; az[2] += v.z * w.x; az[3] += v.w * w.x;
                    arr[0] += v.x * w.y; arr[1] += v.y * w.y; arr[2] += v.z * w.y; arr[3] += v.w * w.y;
                    axh[0] += v.x * w.z; axh[1] += v.y * w.z; axh[2] += v.z * w.z; axh[3] += v.w * w.z;
                }
            }
        }
        // ---- in-wave split-K reduce ----
        #pragma unroll
        for (int m = 1; m <= 4; m <<= 1) {
            #pragma unroll
            for (int i = 0; i < 4; ++i) {
                az[i] += __shfl_xor(az[i], m, 64);
                arr[i] += __shfl_xor(arr[i], m, 64);
                ahh[i] += __shfl_xor(ahh[i], m, 64);
                axh[i] += __shfl_xor(axh[i], m, 64);
            }
        }
        if (kp == 0) {
            #pragma unroll
            for (int i = 0; i < 4; ++i) {
                int r = rg * 4 + i;
                float z = sigmoidf_(az[i] + bz_in + bz_rc);
                float rr = sigmoidf_(arr[i] + br_in + br_rc);
                float cc = tanhf(axh[i] + bc_in + rr * (ahh[i] + bc_rc));
                float hold = hprev[j * 32 + r];
                float hnew = z * hold + (1.0f - z) * cc;
                store_agent(&hnext[j * 32 + r], hnew);     // write-through: no wbl2 at barrier
                enc[((size_t)r * SS + t) * UU + j] = hnew; // cross-kernel only: normal store
            }
        }
        grid_barrier(bar, grp, (unsigned)t);
    }
}

// ---------------- generic fp32 GEMM: C[M,N] = A[M,K]@B[K,N] + bias ----------------
__global__ __launch_bounds__(256) void k_gemm(const float* __restrict__ A,
                                              const float* __restrict__ Bm,
                                              const float* __restrict__ bias,
                                              float* __restrict__ C,
                                              int M, int N, int K) {
    __shared__ float As[16][68];
    __shared__ float Bs[16][132];
    const int rb = blockIdx.x * 64;
    const int cb = blockIdx.y * 128;
    const int tid = threadIdx.x;
    const int cg = tid & 31;
    const int rg = tid >> 5;
    float acc[8][4] = {{0.f}};

    const int arow = tid >> 2, akq = (tid & 3) * 4;
    const int bkk = tid >> 4, bc8 = (tid & 15) * 8;
    const bool nfull = (cb + 128 <= N);

    for (int k0 = 0; k0 < K; k0 += 16) {
        {
            float4 a4 = *(const float4*)(A + (size_t)(rb + arow) * K + k0 + akq);
            As[akq + 0][arow] = a4.x; As[akq + 1][arow] = a4.y;
            As[akq + 2][arow] = a4.z; As[akq + 3][arow] = a4.w;
        }
        {
            int col = cb + bc8;
            const float* bp = Bm + (size_t)(k0 + bkk) * N + col;
            if (nfull) {
                float4 x0 = *(const float4*)bp;
                float4 x1 = *(const float4*)(bp + 4);
                Bs[bkk][bc8 + 0] = x0.x; Bs[bkk][bc8 + 1] = x0.y; Bs[bkk][bc8 + 2] = x0.z; Bs[bkk][bc8 + 3] = x0.w;
                Bs[bkk][bc8 + 4] = x1.x; Bs[bkk][bc8 + 5] = x1.y; Bs[bkk][bc8 + 6] = x1.z; Bs[bkk][bc8 + 7] = x1.w;
            } else {
                #pragma unroll
                for (int jj = 0; jj < 8; ++jj)
                    Bs[bkk][bc8 + jj] = (col + jj < N) ? bp[jj] : 0.0f;
            }
        }
        __syncthreads();
        #pragma unroll
        for (int kk = 0; kk < 16; ++kk) {
            float4 a0 = *(const float4*)&As[kk][rg * 8];
            float4 a1 = *(const float4*)&As[kk][rg * 8 + 4];
            float4 b0 = *(const float4*)&Bs[kk][cg * 4];
            float av[8] = {a0.x, a0.y, a0.z, a0.w, a1.x, a1.y, a1.z, a1.w};
            float bv[4] = {b0.x, b0.y, b0.z, b0.w};
            #pragma unroll
            for (int i = 0; i < 8; ++i)
                #pragma unroll
                for (int jj = 0; jj < 4; ++jj)
                    acc[i][jj] += av[i] * bv[jj];
        }
        __syncthreads();
    }
    const int col0 = cb + cg * 4;
    const bool cfull = (col0 + 4 <= N);
    #pragma unroll
    for (int i = 0; i < 8; ++i) {
        int row = rb + rg * 8 + i;
        float* cp = C + (size_t)row * N + col0;
        if (cfull) {
            float4 o;
            o.x = acc[i][0] + bias[col0 + 0];
            o.y = acc[i][1] + bias[col0 + 1];
            o.z = acc[i][2] + bias[col0 + 2];
            o.w = acc[i][3] + bias[col0 + 3];
            *(float4*)cp = o;
        } else {
            #pragma unroll
            for (int jj = 0; jj < 4; ++jj)
                if (col0 + jj < N) cp[jj] = acc[i][jj] + bias[col0 + jj];
        }
    }
}

// ---------------- decoder: 16 steps x 4 phases, persistent grid ----------------
__global__ __launch_bounds__(256, 1) void k_decoder(const float* __restrict__ W2,
                                                    const float* __restrict__ b2,
                                                    const float* __restrict__ Va,
                                                    const float* __restrict__ bv,
                                                    const float* __restrict__ Wxd,
                                                    const float* __restrict__ b_rec,
                                                    float* __restrict__ ws) {
    float* hT = ws + WS_HT;            // slot 0 = encoder final hidden
    float* enc = ws + WS_ENC;
    float* pre = ws + WS_PRE;
    float* q = ws + WS_Q;
    float* esc = ws + WS_ESC;
    float* xT = ws + WS_XT;
    float* hdT = ws + WS_HDT;
    float* Hd = ws + WS_HD;
    float* GXd = ws + WS_GXD;
    unsigned* bar = (unsigned*)(ws + WS_BAR) + 1024;

    __shared__ float Wxds[16384];      // [wv][k][4]
    __shared__ float eL[64];
    __shared__ float attnL[64];
    __shared__ float shs[256];

    const int tid = threadIdx.x;
    const int bid = blockIdx.x;
    const int grp = bid & 7;
    const int wv = tid >> 6;
    const int lane = tid & 63;

    for (int k = tid; k < 1024; k += 256) {
        #pragma unroll
        for (int g = 0; g < 3; ++g) {
            float4 v = *(const float4*)(Wxd + (size_t)k * G3 + g * 1024 + bid * 4);
            Wxds[0 * 4096 + k * 4 + g] = v.x;
            Wxds[1 * 4096 + k * 4 + g] = v.y;
            Wxds[2 * 4096 + k * 4 + g] = v.z;
            Wxds[3 * 4096 + k * 4 + g] = v.w;
        }
    }
    __syncthreads();

    const float* wxb = Wxds + wv * 4096;
    const int j4 = bid * 4 + wv;
    const float bz_rc = b_rec[j4], br_rc = b_rec[1024 + j4], bc_rc = b_rec[2048 + j4];
    unsigned bc = 0;

    for (int t = 0; t < TT; ++t) {
        const float* hsrc = (t == 0) ? hT : hdT;

        // ---- S1: q = dec_h @ W2 + b2 (4 q-cols per block) ----
        {
            const int cq = lane & 3;
            const int kp = (lane >> 2) & 7;
            const int rgq = (lane >> 5) | (wv << 1);
            const int qc = bid * 4 + cq;
            const float* hp = hsrc + kp * 32 + rgq * 4;
            const float* wp = W2 + (size_t)kp * UU + qc;
            float a0 = 0, a1 = 0, a2 = 0, a3 = 0;
            for (int g = 0; g < 16; ++g) {
                float4 hv[8]; float wr[8];
                #pragma unroll
                for (int u = 0; u < 8; ++u) {
                    hv[u] = *(const float4*)(hp + (g * 8 + u) * 256);
                    wr[u] = wp[(size_t)(g * 8 + u) * 8 * UU];
                }
                #pragma unroll
                for (int u = 0; u < 8; ++u) {
                    a0 += hv[u].x * wr[u]; a1 += hv[u].y * wr[u];
                    a2 += hv[u].z * wr[u]; a3 += hv[u].w * wr[u];
                }
            }
            #pragma unroll
            for (int m = 4; m <= 16; m <<= 1) {
                a0 += __shfl_xor(a0, m, 64); a1 += __shfl_xor(a1, m, 64);
                a2 += __shfl_xor(a2, m, 64); a3 += __shfl_xor(a3, m, 64);
            }
            if (((lane >> 2) & 7) == 0) {
                float bb2 = b2[qc];
                store_agent(&q[(size_t)(rgq * 4 + 0) * UU + qc], a0 + bb2);
                store_agent(&q[(size_t)(rgq * 4 + 1) * UU + qc], a1 + bb2);
                store_agent(&q[(size_t)(rgq * 4 + 2) * UU + qc], a2 + bb2);
                store_agent(&q[(size_t)(rgq * 4 + 3) * UU + qc], a3 + bb2);
            }
        }
        grid_barrier(bar, grp, bc++);

        // ---- S2: scores e[b][s] = tanh(pre_enc + q) . Va + bv ----
        {
            const int b = bid >> 3, s0 = (bid & 7) * 8;
            const int pi = tid >> 5, kq = tid & 31;
            const int srow = s0 + pi;
            const float* pe = pre + ((size_t)b * SS + srow) * UU;
            const float* qb = q + (size_t)b * UU;
            float acc = 0;
            #pragma unroll
            for (int kk = 0; kk < 8; ++kk) {
                int k = kq * 32 + kk * 4;
                float4 p4 = *(const float4*)(pe + k);
                float4 q4 = *(const float4*)(qb + k);
                float4 v4 = *(const float4*)(Va + k);
                acc += tanhf(p4.x + q4.x) * v4.x + tanhf(p4.y + q4.y) * v4.y +
                       tanhf(p4.z + q4.z) * v4.z + tanhf(p4.w + q4.w) * v4.w;
            }
            #pragma unroll
            for (int m = 16; m >= 1; m >>= 1) acc += __shfl_xor(acc, m, 32);
            if (kq == 0) store_agent(&esc[b * SS + srow], acc + bv[0]);
        }
        grid_barrier(bar, grp, bc++);

        // ---- S3: softmax + ctx (coalesced over U) into xT ----
        {
            const int b = bid >> 3, ug = bid & 7;
            if (tid < 64) eL[tid] = esc[b * SS + tid];
            __syncthreads();
            if (tid < 64) {
                float v = eL[tid];
                float m = v;
                #pragma unroll
                for (int mm = 32; mm >= 1; mm >>= 1) m = fmaxf(m, __shfl_xor(m, mm, 64));
                float p = expf(v - m);
                float sum = p;
                #pragma unroll
                for (int mm = 32; mm >= 1; mm >>= 1) sum += __shfl_xor(sum, mm, 64);
                attnL[tid] = p / sum;
            }
            __syncthreads();
            const int u = ug * 128 + (tid & 127), sp = tid >> 7;
            float acc = 0;
            #pragma unroll 8
            for (int i = 0; i < 32; ++i) {
                int srow = sp * 32 + i;
                acc += attnL[srow] * enc[((size_t)b * SS + srow) * UU + u];
            }
            shs[(tid & 127) * 2 + sp] = acc;
            __syncthreads();
            if (tid < 128)
                store_agent(&xT[(size_t)(ug * 128 + tid) * BB + b], shs[tid * 2] + shs[tid * 2 + 1]);
        }
        grid_barrier(bar, grp, bc++);

        // ---- S4: gx = ctx @ Wxd_top (+ GXd), gates with gh = b_rec, h_new ----
        {
            const int kp = lane & 7;
            const int rg = lane >> 3;
            float sz[4] = {0.f, 0.f, 0.f, 0.f};
            float sr[4] = {0.f, 0.f, 0.f, 0.f};
            float sc[4] = {0.f, 0.f, 0.f, 0.f};
            const float* xp = xT + kp * 32 + rg * 4;
            float4 cbuf[16], nbuf[16];
            #pragma unroll
            for (int u = 0; u < 16; ++u) cbuf[u] = *(const float4*)(xp + u * 256);
            #pragma unroll
            for (int g = 0; g < 8; ++g) {
                if (g < 7) {
                    #pragma unroll
                    for (int u = 0; u < 16; ++u)
                        nbuf[u] = *(const float4*)(xp + ((g + 1) * 16 + u) * 256);
                }
                #pragma unroll
                for (int u = 0; u < 16; ++u) {
                    int k = kp + 8 * (g * 16 + u);
                    float4 w = *(const float4*)(wxb + k * 4);
                    float4 v = cbuf[u];
                    sz[0] += v.x * w.x; sz[1] += v.y * w.x; sz[2] += v.z * w.x; sz[3] += v.w * w.x;
                    sr[0] += v.x * w.y; sr[1] += v.y * w.y; sr[2] += v.z * w.y; sr[3] += v.w * w.y;
                    sc[0] += v.x * w.z; sc[1] += v.y * w.z; sc[2] += v.z * w.z; sc[3] += v.w * w.z;
                }
                if (g < 7) {
                    #pragma unroll
                    for (int u = 0; u < 16; ++u) cbuf[u] = nbuf[u];
                }
            }
            #pragma unroll
            for (int m = 1; m <= 4; m <<= 1) {
                #pragma unroll
                for (int i = 0; i < 4; ++i) {
                    sz[i] += __shfl_xor(sz[i], m, 64);
                    sr[i] += __shfl_xor(sr[i], m, 64);
                    sc[i] += __shfl_xor(sc[i], m, 64);
                }
            }
            if (kp == 0) {
                #pragma unroll
                for (int i = 0; i < 4; ++i) {
                    int r = rg * 4 + i;
                    const float* gx = GXd + (size_t)(t * BB + r) * G3;
                    float xz = sz[i] + gx[j4];
                    float xr = sr[i] + gx[1024 + j4];
                    float xc = sc[i] + gx[2048 + j4];
                    float z = sigmoidf_(xz + bz_rc);
                    float rr = sigmoidf_(xr + br_rc);
                    float cc = tanhf(xc + rr * bc_rc);
                    float h = (1.0f - z) * cc;       // z*h0 + (1-z)*c, h0 = 0
                    Hd[((size_t)r * TT + t) * UU + j4] = h;   // cross-kernel: normal
                    store_agent(&hdT[(size_t)j4 * BB + r], h);
                }
            }
        }
        grid_barrier(bar, grp, bc++);
    }
}

// ---------------- argmax with numpy first-index tie-break ----------------
__global__ __launch_bounds__(256) void k_argmax(const float* __restrict__ logits,
                                                float* __restrict__ outp) {
    const int row = blockIdx.x;
    const float* lr = logits + (size_t)row * VV;
    const int tid = threadIdx.x;
    float best = -INFINITY;
    int bidx = 0x7fffffff;
    for (int c = tid; c < VV; c += 256) {
        float v = lr[c];
        if (v > best) { best = v; bidx = c; }
    }
    __shared__ float bv_[256];
    __shared__ int bi_[256];
    bv_[tid] = best; bi_[tid] = bidx;
    __syncthreads();
    for (int s2 = 128; s2 > 0; s2 >>= 1) {
        if (tid < s2) {
            float ov = bv_[tid + s2]; int oi = bi_[tid + s2];
            if (ov > bv_[tid] || (ov == bv_[tid] && oi < bi_[tid])) {
                bv_[tid] = ov; bi_[tid] = oi;
            }
        }
        __syncthreads();
    }
    if (tid == 0) outp[row] = (float)bi_[0];
}

extern "C" void kernel_launch(void* const* d_in, const int* in_sizes, int n_in,
                              void* d_out, int out_size, void* d_ws, size_t ws_size,
                              hipStream_t stream) {
    const int* enc_in = (const int*)d_in[0];
    const int* teacher = (const int*)d_in[1];
    const float* Ee = (const float*)d_in[4];
    const float* eWx = (const float*)d_in[5];
    const float* eWh = (const float*)d_in[6];
    const float* eb_in = (const float*)d_in[7];
    const float* eb_rec = (const float*)d_in[8];
    const float* Ed = (const float*)d_in[9];
    const float* dWx = (const float*)d_in[10];
    // d_in[11] dec_Wh structurally unused: h0_dec == 0 -> gh == b_rec
    const float* db_in = (const float*)d_in[12];
    const float* db_rec = (const float*)d_in[13];
    const float* W1 = (const float*)d_in[14];
    const float* b1 = (const float*)d_in[15];
    const float* W2 = (const float*)d_in[16];
    const float* b2 = (const float*)d_in[17];
    const float* Va = (const float*)d_in[18];
    const float* bvv = (const float*)d_in[19];
    const float* Wf = (const float*)d_in[20];
    const float* bf = (const float*)d_in[21];
    float* ws = (float*)d_ws;
    float* out = (float*)d_out;

    // prep: XembT gather + hT slot0 zero + Demb gather + barrier zero (3 sets)
    const int NTOT = SS * EE * BB + UU * BB + BB * TT * EE + 3072;
    k_prep<<<dim3((NTOT + 255) / 256), dim3(256), 0, stream>>>(enc_in, Ee, teacher, Ed, ws);

    // diagnostic: pure-barrier cost (dur_us / 64 = per-barrier). Remove next round.
    k_bartest<<<dim3(NBLK), dim3(256), 0, stream>>>(ws);

    // GXd = Demb @ dec_Wx[1024:1280,:] + dec_b_in : [512,256]x[256,3072]
    k_gemm<<<dim3(8, 24), dim3(256), 0, stream>>>(ws + WS_DEMB, dWx + (size_t)UU * G3, db_in,
                                                  ws + WS_GXD, BB * TT, G3, EE);

    // encoder recurrence (persistent, 64 steps)
    k_encoder<<<dim3(NBLK), dim3(256), 0, stream>>>(eWh, eWx, eb_in, eb_rec, ws);

    // pre_enc = encoded @ W1 + b1 : [2048,1024]x[1024,1024]
    k_gemm<<<dim3(32, 8), dim3(256), 0, stream>>>(ws + WS_ENC, W1, b1, ws + WS_PRE, BB * SS, UU, UU);

    // decoder (persistent, 16 steps x 4 phases)
    k_decoder<<<dim3(NBLK), dim3(256), 0, stream>>>(W2, b2, Va, bvv, dWx, db_rec, ws);

    // logits = Hdec @ Wf + bf : [512,1024]x[1024,20200] -> d_out
    k_gemm<<<dim3(8, 158), dim3(256), 0, stream>>>(ws + WS_HD, Wf, bf, out, BB * TT, VV, UU);

    // predictions = argmax(logits)
    k_argmax<<<dim3(BB * TT), dim3(256), 0, stream>>>(out, out + (size_t)BB * TT * VV);
}